// Round 3
// baseline (659.860 us; speedup 1.0000x reference)
//
#include <hip/hip_runtime.h>

// ---------------------------------------------------------------------------
// Linformer self-attention, fp32 I/O, fp16 MFMA internally, MI355X (gfx950)
// b=4 n=4096 d=1024 h=16 dh=64 k=256   (no 1/sqrt(dh) scale per reference)
//
// Pipeline (all on `stream`, ws reused):
//   1. gemm_xw : X[16384,1024](f32) @ W(f32) -> buf0 (f16)     (x3: K, V, Q)
//   2. proj_tn : C[I,J] = sum_n A[n,I]*B[n,J]  (mixed f32/f16 in, f16 out)
//   3. attn_k  : per (b,h) strip of 16 Q rows: QK^T -> softmax -> PV -> f32 out
// ---------------------------------------------------------------------------

typedef __fp16 f16x8 __attribute__((ext_vector_type(8)));
typedef __fp16 f16x2 __attribute__((ext_vector_type(2)));
typedef float fl4 __attribute__((ext_vector_type(4)));
typedef float f32x4 __attribute__((ext_vector_type(4)));
typedef unsigned short u16x4 __attribute__((ext_vector_type(4)));

#define MFMA16(a, b, c) __builtin_amdgcn_mfma_f32_16x16x32_f16((a), (b), (c), 0, 0, 0)

__device__ __forceinline__ unsigned int pk2u(float a, float b) {
  f16x2 p = __builtin_amdgcn_cvt_pkrtz(a, b);  // low = a, high = b
  return __builtin_bit_cast(unsigned int, p);
}

__device__ __forceinline__ f16x8 pk8(fl4 a, fl4 b) {
  f16x2 p0 = __builtin_amdgcn_cvt_pkrtz(a[0], a[1]);
  f16x2 p1 = __builtin_amdgcn_cvt_pkrtz(a[2], a[3]);
  f16x2 p2 = __builtin_amdgcn_cvt_pkrtz(b[0], b[1]);
  f16x2 p3 = __builtin_amdgcn_cvt_pkrtz(b[2], b[3]);
  f16x8 r;
  r[0] = p0[0]; r[1] = p0[1]; r[2] = p1[0]; r[3] = p1[1];
  r[4] = p2[0]; r[5] = p2[1]; r[6] = p3[0]; r[7] = p3[1];
  return r;
}

// ---------------------------------------------------------------------------
// Kernel 1: C[16384,1024](f16) = X[16384,1024](f32) @ W[1024,1024](f32)
// 128x128 tile, BK=32, 4 waves (2x2), 64x64 per wave = 4x4 frags.
// X tile -> LDS [m][k] stride 40 (reg-staged, cvt to f16).
// W tile -> LDS transposed [n][k] stride 40 (reg-staged, pair-packed).
// ---------------------------------------------------------------------------
__global__ __launch_bounds__(256) void gemm_xw(
    const float* __restrict__ X,
    const float* __restrict__ W,
    __fp16* __restrict__ C) {
  constexpr int K = 1024, N = 1024;
  __shared__ __fp16 Xs[128 * 40];
  __shared__ __fp16 Wst[128 * 40];
  const int t = threadIdx.x;
  const int lane = t & 63, w = t >> 6;
  const int lr = lane & 15, lg = lane >> 4;
  const int m0 = blockIdx.x * 128, n0 = blockIdx.y * 128;
  const int wr = (w >> 1) * 64, wc = (w & 1) * 64;

  f32x4 acc[4][4];
#pragma unroll
  for (int i = 0; i < 4; ++i)
#pragma unroll
    for (int j = 0; j < 4; ++j) acc[i][j] = (f32x4){0.f, 0.f, 0.f, 0.f};

  // X staging: thread t -> row t>>1, 16 cols starting at (t&1)*16
  const int xr = t >> 1, xc = (t & 1) * 16;
  // W staging: k-rows wp2, wp2+1; 8 cols starting at wc0
  const int wp2 = (t >> 4) * 2, wc0 = (t & 15) * 8;
  const float* Xp = X + (size_t)(m0 + xr) * K + xc;
  const float* Wp0 = W + (size_t)wp2 * N + n0 + wc0;

  for (int k0 = 0; k0 < K; k0 += 32) {
    // prefetch loads (global) before the barrier
    fl4 x0 = *(const fl4*)(Xp + k0);
    fl4 x1 = *(const fl4*)(Xp + k0 + 4);
    fl4 x2 = *(const fl4*)(Xp + k0 + 8);
    fl4 x3 = *(const fl4*)(Xp + k0 + 12);
    const float* wrow = Wp0 + (size_t)k0 * N;
    fl4 wa0 = *(const fl4*)(wrow);
    fl4 wa1 = *(const fl4*)(wrow + 4);
    fl4 wb0 = *(const fl4*)(wrow + N);
    fl4 wb1 = *(const fl4*)(wrow + N + 4);
    __syncthreads();  // previous iteration's readers done
    *(f16x8*)&Xs[xr * 40 + xc] = pk8(x0, x1);
    *(f16x8*)&Xs[xr * 40 + xc + 8] = pk8(x2, x3);
#pragma unroll
    for (int j = 0; j < 4; ++j) {
      *(unsigned int*)&Wst[(wc0 + j) * 40 + wp2] = pk2u(wa0[j], wb0[j]);
      *(unsigned int*)&Wst[(wc0 + 4 + j) * 40 + wp2] = pk2u(wa1[j], wb1[j]);
    }
    __syncthreads();  // staging visible

    f16x8 af[4], bfr[4];
#pragma unroll
    for (int i = 0; i < 4; ++i)
      af[i] = *(const f16x8*)&Xs[(wr + i * 16 + lr) * 40 + lg * 8];
#pragma unroll
    for (int j = 0; j < 4; ++j)
      bfr[j] = *(const f16x8*)&Wst[(wc + j * 16 + lr) * 40 + lg * 8];
#pragma unroll
    for (int i = 0; i < 4; ++i)
#pragma unroll
      for (int j = 0; j < 4; ++j)
        acc[i][j] = MFMA16(af[i], bfr[j], acc[i][j]);
  }

#pragma unroll
  for (int i = 0; i < 4; ++i)
#pragma unroll
    for (int j = 0; j < 4; ++j)
#pragma unroll
      for (int r = 0; r < 4; ++r) {
        const int row = m0 + wr + i * 16 + lg * 4 + r;
        const int col = n0 + wc + j * 16 + lr;
        C[(size_t)row * N + col] = (__fp16)acc[i][j][r];
      }
}

// ---------------------------------------------------------------------------
// Kernel 2: C[I,J](f16) = sum_{n<4096} A[n,I] * B[n,J]  (TN, 64x64 tile, BK=32)
// AF/BF: 1 = operand is f32 (convert while packing), 0 = f16.
// Both tiles reg-transposed into LDS [64][40]. grid = (I/64, J/64, batch).
// ---------------------------------------------------------------------------
template <int AF, int BF>
__global__ __launch_bounds__(256) void proj_tn(
    const void* __restrict__ A_, int sA, long long bsA,
    const void* __restrict__ B_, int sB, long long bsB,
    __fp16* __restrict__ C, int ldC, long long bsC) {
  __shared__ __fp16 At[64 * 40];
  __shared__ __fp16 Bt[64 * 40];
  const int t = threadIdx.x;
  const int lane = t & 63, w = t >> 6;
  const int lr = lane & 15, lg = lane >> 4;
  const int i0 = blockIdx.x * 64, j0 = blockIdx.y * 64;
  C += (size_t)blockIdx.z * (size_t)bsC;
  const int wr = (w >> 1) * 32, wc = (w & 1) * 32;

  f32x4 acc[2][2];
#pragma unroll
  for (int i = 0; i < 2; ++i)
#pragma unroll
    for (int j = 0; j < 2; ++j) acc[i][j] = (f32x4){0.f, 0.f, 0.f, 0.f};

  const int p2 = (t >> 4) * 2;   // n-local row pair
  const int c0 = (t & 15) * 4;   // 4 cols per thread

  for (int n0 = 0; n0 < 4096; n0 += 32) {
    unsigned int pa[4], pb[4];
    if constexpr (AF) {
      const float* A = (const float*)A_ + (size_t)blockIdx.z * (size_t)bsA;
      fl4 a0 = *(const fl4*)(A + (size_t)(n0 + p2) * sA + i0 + c0);
      fl4 a1 = *(const fl4*)(A + (size_t)(n0 + p2 + 1) * sA + i0 + c0);
#pragma unroll
      for (int j = 0; j < 4; ++j) pa[j] = pk2u(a0[j], a1[j]);
    } else {
      const unsigned short* A = (const unsigned short*)A_ + (size_t)blockIdx.z * (size_t)bsA;
      u16x4 a0 = *(const u16x4*)(A + (size_t)(n0 + p2) * sA + i0 + c0);
      u16x4 a1 = *(const u16x4*)(A + (size_t)(n0 + p2 + 1) * sA + i0 + c0);
#pragma unroll
      for (int j = 0; j < 4; ++j) pa[j] = (unsigned)a0[j] | ((unsigned)a1[j] << 16);
    }
    if constexpr (BF) {
      const float* B = (const float*)B_ + (size_t)blockIdx.z * (size_t)bsB;
      fl4 b0 = *(const fl4*)(B + (size_t)(n0 + p2) * sB + j0 + c0);
      fl4 b1 = *(const fl4*)(B + (size_t)(n0 + p2 + 1) * sB + j0 + c0);
#pragma unroll
      for (int j = 0; j < 4; ++j) pb[j] = pk2u(b0[j], b1[j]);
    } else {
      const unsigned short* B = (const unsigned short*)B_ + (size_t)blockIdx.z * (size_t)bsB;
      u16x4 b0 = *(const u16x4*)(B + (size_t)(n0 + p2) * sB + j0 + c0);
      u16x4 b1 = *(const u16x4*)(B + (size_t)(n0 + p2 + 1) * sB + j0 + c0);
#pragma unroll
      for (int j = 0; j < 4; ++j) pb[j] = (unsigned)b0[j] | ((unsigned)b1[j] << 16);
    }
    __syncthreads();
#pragma unroll
    for (int j = 0; j < 4; ++j) {
      *(unsigned int*)&At[(c0 + j) * 40 + p2] = pa[j];
      *(unsigned int*)&Bt[(c0 + j) * 40 + p2] = pb[j];
    }
    __syncthreads();

    f16x8 af[2], bfr[2];
#pragma unroll
    for (int i = 0; i < 2; ++i)
      af[i] = *(const f16x8*)&At[(wr + i * 16 + lr) * 40 + lg * 8];
#pragma unroll
    for (int j = 0; j < 2; ++j)
      bfr[j] = *(const f16x8*)&Bt[(wc + j * 16 + lr) * 40 + lg * 8];
#pragma unroll
    for (int i = 0; i < 2; ++i)
#pragma unroll
      for (int j = 0; j < 2; ++j)
        acc[i][j] = MFMA16(af[i], bfr[j], acc[i][j]);
  }

#pragma unroll
  for (int i = 0; i < 2; ++i)
#pragma unroll
    for (int j = 0; j < 2; ++j)
#pragma unroll
      for (int r = 0; r < 4; ++r) {
        const int row = i0 + wr + i * 16 + lg * 4 + r;
        const int col = j0 + wc + j * 16 + lr;
        C[(size_t)row * ldC + col] = (__fp16)acc[i][j][r];
      }
}

// ---------------------------------------------------------------------------
// Kernel 3: attention. One wave = one 16-row Q strip of one (b,h).
// dots[16 rows][256] in regs (16 f32x4 frags) -> shfl softmax -> P via LDS
// transpose (stride 264) -> PV with VpT read from L2. Output fp32.
// grid 4096 x 256thr: blockIdx/64 = (b,h); 4 waves x 64 strip-groups.
// ---------------------------------------------------------------------------
__global__ __launch_bounds__(256) void attn_k(
    const __fp16* __restrict__ Q,    // [b*4096][1024] f16
    const __fp16* __restrict__ Kp,   // [b][256][1024] f16
    const __fp16* __restrict__ Vpt,  // [b][1024][256] f16
    float* __restrict__ O) {         // [b*4096][1024] f32
  __shared__ __fp16 P[4][16 * 264];  // per-wave P strip, pad 264
  const int t = threadIdx.x;
  const int lane = t & 63, w = t >> 6;
  const int lr = lane & 15, lg = lane >> 4;
  const int bh = blockIdx.x >> 6;
  const int sg = blockIdx.x & 63;
  const int b = bh >> 4, h = bh & 15;
  const int m0 = (sg * 4 + w) * 16;

  const __fp16* Qh = Q + ((size_t)(b * 4096 + m0)) * 1024 + h * 64;
  const __fp16* Kph = Kp + (size_t)b * 256 * 1024 + h * 64;
  const __fp16* Vph = Vpt + ((size_t)b * 1024 + h * 64) * 256;

  // Q fragments (A-operand): row lr, k = lg*8.. (+32 for the 2nd K-step)
  f16x8 aq0 = *(const f16x8*)(Qh + (size_t)lr * 1024 + lg * 8);
  f16x8 aq1 = *(const f16x8*)(Qh + (size_t)lr * 1024 + 32 + lg * 8);

  // dots = Q . Kp^T : 16 col-tiles x (dh/32 = 2 K-steps)
  f32x4 dots[16];
#pragma unroll
  for (int jt = 0; jt < 16; ++jt) {
    f16x8 k0 = *(const f16x8*)(Kph + (size_t)(jt * 16 + lr) * 1024 + lg * 8);
    f16x8 k1 = *(const f16x8*)(Kph + (size_t)(jt * 16 + lr) * 1024 + 32 + lg * 8);
    f32x4 d = (f32x4){0.f, 0.f, 0.f, 0.f};
    d = MFMA16(aq0, k0, d);
    d = MFMA16(aq1, k1, d);
    dots[jt] = d;
  }

  // softmax over 256 per row; lane holds col lr of rows lg*4+r
  float mx[4], sm[4];
#pragma unroll
  for (int r = 0; r < 4; ++r) mx[r] = -1e30f;
#pragma unroll
  for (int jt = 0; jt < 16; ++jt)
#pragma unroll
    for (int r = 0; r < 4; ++r) mx[r] = fmaxf(mx[r], dots[jt][r]);
#pragma unroll
  for (int msk = 1; msk <= 8; msk <<= 1)
#pragma unroll
    for (int r = 0; r < 4; ++r) mx[r] = fmaxf(mx[r], __shfl_xor(mx[r], msk, 64));
#pragma unroll
  for (int r = 0; r < 4; ++r) sm[r] = 0.f;
#pragma unroll
  for (int jt = 0; jt < 16; ++jt)
#pragma unroll
    for (int r = 0; r < 4; ++r) {
      float p = __expf(dots[jt][r] - mx[r]);
      dots[jt][r] = p;
      sm[r] += p;
    }
#pragma unroll
  for (int msk = 1; msk <= 8; msk <<= 1)
#pragma unroll
    for (int r = 0; r < 4; ++r) sm[r] += __shfl_xor(sm[r], msk, 64);

  // P -> LDS (transpose from D-layout to A-fragment layout)
  __fp16* Pw = &P[w][0];
#pragma unroll
  for (int jt = 0; jt < 16; ++jt)
#pragma unroll
    for (int r = 0; r < 4; ++r)
      Pw[(lg * 4 + r) * 264 + jt * 16 + lr] = (__fp16)dots[jt][r];
  __syncthreads();

  // out = P @ Vp : VpT[dd][kk] read from global (L2-resident, 32KB/head)
  f32x4 o[4];
#pragma unroll
  for (int j = 0; j < 4; ++j) o[j] = (f32x4){0.f, 0.f, 0.f, 0.f};
#pragma unroll
  for (int ks = 0; ks < 8; ++ks) {
    f16x8 pa = *(const f16x8*)&Pw[lr * 264 + ks * 32 + lg * 8];
#pragma unroll
    for (int jt2 = 0; jt2 < 4; ++jt2) {
      f16x8 bv = *(const f16x8*)(Vph + (size_t)(jt2 * 16 + lr) * 256 + ks * 32 + lg * 8);
      o[jt2] = MFMA16(pa, bv, o[jt2]);
    }
  }

  float rs[4];
#pragma unroll
  for (int r = 0; r < 4; ++r) rs[r] = 1.f / sm[r];
#pragma unroll
  for (int jt2 = 0; jt2 < 4; ++jt2)
#pragma unroll
    for (int r = 0; r < 4; ++r) {
      const size_t row = (size_t)(b * 4096 + m0 + lg * 4 + r);
      O[row * 1024 + h * 64 + jt2 * 16 + lr] = o[jt2][r] * rs[r];
    }
}

// ---------------------------------------------------------------------------
extern "C" void kernel_launch(void* const* d_in, const int* in_sizes, int n_in,
                              void* d_out, int out_size, void* d_ws, size_t ws_size,
                              hipStream_t stream) {
  (void)in_sizes; (void)n_in; (void)out_size; (void)ws_size;
  const float* x  = (const float*)d_in[0];
  const float* Wq = (const float*)d_in[1];
  const float* Wk = (const float*)d_in[2];
  const float* Wv = (const float*)d_in[3];
  const float* pk = (const float*)d_in[4];
  const float* pv = (const float*)d_in[5];
  float* out = (float*)d_out;

  // ws layout (f16): buf0 (33.5MB, reused K->V->Q) | Kp (2MB) | VpT (2MB)
  __fp16* buf0 = (__fp16*)d_ws;
  __fp16* Kp = buf0 + (size_t)16384 * 1024;
  __fp16* Vpt = Kp + (size_t)4 * 256 * 1024;

  const dim3 bb(256);
  const dim3 gg(128, 8);  // 16384/128 x 1024/128

  // K path: Kmat = X@Wk ; Kp[b,kk,dd] = sum_n proj_k[n,kk] * Kmat[b,n,dd]
  gemm_xw<<<gg, bb, 0, stream>>>(x, Wk, buf0);
  proj_tn<1, 0><<<dim3(4, 16, 4), bb, 0, stream>>>(
      pk, 256, 0LL, buf0, 1024, 4096LL * 1024, Kp, 1024, 256LL * 1024);
  // V path: Vmat = X@Wv ; VpT[b,dd,kk] = sum_n Vmat[b,n,dd] * proj_v[n,kk]
  gemm_xw<<<gg, bb, 0, stream>>>(x, Wv, buf0);
  proj_tn<0, 1><<<dim3(16, 4, 4), bb, 0, stream>>>(
      buf0, 1024, 4096LL * 1024, pv, 256, 0LL, Vpt, 256, 1024LL * 256);
  // Q path + attention
  gemm_xw<<<gg, bb, 0, stream>>>(x, Wq, buf0);
  attn_k<<<dim3(4096), bb, 0, stream>>>(buf0, Kp, Vpt, out);
}

// Round 4
// 323.440 us; speedup vs baseline: 2.0401x; 2.0401x over previous
//
#include <hip/hip_runtime.h>

// ---------------------------------------------------------------------------
// Linformer self-attention, fp32 I/O, fp16 MFMA internally, MI355X (gfx950)
// b=4 n=4096 d=1024 h=16 dh=64 k=256  (no 1/sqrt(dh) scale per reference)
//
// Key algebra: proj_k^T (X Wk) == (proj_k^T X) Wk  -> K/V paths cost 4x less.
// Pipeline:
//   0. tr_cvt   : W^T, pk^T, pv^T  (f32 -> f16, one-time)
//   1. stage1   : Xk[b,256,1024] = pkT . X ; Xv = pvT . X   (fused, shares X^T tile)
//   2. bt64     : Kp[b,256,1024] = Xk . WkT^T ; VpT[b,1024,256] = WvT . Xv^T
//   3. gemm_q   : Qh[16384,1024] = X . WqT^T   (128x128, global_load_lds B-side)
//   4. attn_k   : per 16-row Q strip: QK^T -> softmax -> PV -> f32 out
// ---------------------------------------------------------------------------

typedef __fp16 f16x8 __attribute__((ext_vector_type(8)));
typedef __fp16 f16x2 __attribute__((ext_vector_type(2)));
typedef float fl4 __attribute__((ext_vector_type(4)));
typedef float f32x4 __attribute__((ext_vector_type(4)));
typedef unsigned int u32x2 __attribute__((ext_vector_type(2)));

#define MFMA16(a, b, c) __builtin_amdgcn_mfma_f32_16x16x32_f16((a), (b), (c), 0, 0, 0)

__device__ __forceinline__ unsigned int pk2u(float a, float b) {
  f16x2 p = __builtin_amdgcn_cvt_pkrtz(a, b);  // low = a, high = b
  return __builtin_bit_cast(unsigned int, p);
}

__device__ __forceinline__ f16x8 pk8(fl4 a, fl4 b) {
  f16x2 p0 = __builtin_amdgcn_cvt_pkrtz(a[0], a[1]);
  f16x2 p1 = __builtin_amdgcn_cvt_pkrtz(a[2], a[3]);
  f16x2 p2 = __builtin_amdgcn_cvt_pkrtz(b[0], b[1]);
  f16x2 p3 = __builtin_amdgcn_cvt_pkrtz(b[2], b[3]);
  f16x8 r;
  r[0] = p0[0]; r[1] = p0[1]; r[2] = p1[0]; r[3] = p1[1];
  r[4] = p2[0]; r[5] = p2[1]; r[6] = p3[0]; r[7] = p3[1];
  return r;
}

__device__ __forceinline__ void gload_lds16(const __fp16* g, void* lds_base) {
  __builtin_amdgcn_global_load_lds(
      (const __attribute__((address_space(1))) void*)g,
      (__attribute__((address_space(3))) void*)lds_base, 16, 0, 0);
}

// ---------------------------------------------------------------------------
// Transpose + convert: in f32 [R][C] -> out f16 [C][R]. 32x32 tiles.
// ---------------------------------------------------------------------------
__global__ __launch_bounds__(256) void tr_cvt(
    const float* __restrict__ in, __fp16* __restrict__ out, int R, int C) {
  __shared__ float tile[32][33];
  const int t = threadIdx.x;
  const int c0 = blockIdx.x * 32, r0 = blockIdx.y * 32;
  {
    const int r = t >> 3, cg = (t & 7) * 4;
    fl4 v = *(const fl4*)(in + (size_t)(r0 + r) * C + c0 + cg);
    tile[r][cg] = v[0]; tile[r][cg + 1] = v[1];
    tile[r][cg + 2] = v[2]; tile[r][cg + 3] = v[3];
  }
  __syncthreads();
  {
    const int cc = t >> 3, rg = (t & 7) * 4;
    u32x2 p;
    p[0] = pk2u(tile[rg + 0][cc], tile[rg + 1][cc]);
    p[1] = pk2u(tile[rg + 2][cc], tile[rg + 3][cc]);
    *(u32x2*)(out + (size_t)(c0 + cc) * R + r0 + rg) = p;
  }
}

// ---------------------------------------------------------------------------
// Stage 1 (fused K+V): Xk[b][kk][dd] = sum_n pkT[kk][n] * X[b][n][dd]
//                      Xv[b][kk][dd] = sum_n pvT[kk][n] * X[b][n][dd]
// 64(kk) x 64(dd) tile, BK=32 over n. pkT/pvT tiles: linear global_load_lds.
// X^T tile [64 dd][32 n]: reg-staged (f32->f16 pack), 16B-block XOR swizzle.
// ---------------------------------------------------------------------------
__global__ __launch_bounds__(256) void stage1(
    const __fp16* __restrict__ pkT,  // [256][4096]
    const __fp16* __restrict__ pvT,  // [256][4096]
    const float* __restrict__ X,     // [b][4096][1024]
    __fp16* __restrict__ Xk,         // [b][256][1024]
    __fp16* __restrict__ Xv) {       // [b][256][1024]
  __shared__ __fp16 Ak[64 * 32];
  __shared__ __fp16 Av[64 * 32];
  __shared__ __fp16 Bt[64 * 32];  // [dd][n], XOR-swizzled 16B blocks
  const int t = threadIdx.x;
  const int lane = t & 63, w = t >> 6;
  const int lr = lane & 15, lg = lane >> 4;
  const int kk0 = blockIdx.x * 64, dd0 = blockIdx.y * 64;
  const int b = blockIdx.z;
  const int wr = (w >> 1) * 32, wc = (w & 1) * 32;

  f32x4 acck[2][2], accv[2][2];
#pragma unroll
  for (int i = 0; i < 2; ++i)
#pragma unroll
    for (int j = 0; j < 2; ++j) {
      acck[i][j] = (f32x4){0.f, 0.f, 0.f, 0.f};
      accv[i][j] = (f32x4){0.f, 0.f, 0.f, 0.f};
    }

  const int grow = t >> 2, gcol = (t & 3) * 8;      // gload indices
  const int np = t >> 4, ddl = (t & 15) * 4;        // X^T staging indices
  const __fp16* pkSrc = pkT + (size_t)(kk0 + grow) * 4096 + gcol;
  const __fp16* pvSrc = pvT + (size_t)(kk0 + grow) * 4096 + gcol;
  const float* xSrc = X + ((size_t)b * 4096 + 2 * np) * 1024 + dd0 + ddl;

  for (int n0 = 0; n0 < 4096; n0 += 32) {
    fl4 x0 = *(const fl4*)(xSrc + (size_t)n0 * 1024);
    fl4 x1 = *(const fl4*)(xSrc + (size_t)(n0 + 1) * 1024);
    __syncthreads();
    gload_lds16(pkSrc + n0, (char*)Ak + w * 1024);
    gload_lds16(pvSrc + n0, (char*)Av + w * 1024);
#pragma unroll
    for (int j = 0; j < 4; ++j) {
      const int dd = ddl + j;
      const int slot = (((np >> 2) ^ ((dd >> 3) & 3)) << 2) + (np & 3);
      *(unsigned int*)&Bt[dd * 32 + slot * 2] = pk2u(x0[j], x1[j]);
    }
    __syncthreads();

    f16x8 ak[2], av[2], bx[2];
#pragma unroll
    for (int i = 0; i < 2; ++i) {
      ak[i] = *(const f16x8*)&Ak[(wr + i * 16 + lr) * 32 + lg * 8];
      av[i] = *(const f16x8*)&Av[(wr + i * 16 + lr) * 32 + lg * 8];
    }
#pragma unroll
    for (int j = 0; j < 2; ++j) {
      const int dd = wc + j * 16 + lr;
      bx[j] = *(const f16x8*)&Bt[dd * 32 + ((lg ^ ((dd >> 3) & 3)) * 8)];
    }
#pragma unroll
    for (int i = 0; i < 2; ++i)
#pragma unroll
      for (int j = 0; j < 2; ++j) {
        acck[i][j] = MFMA16(ak[i], bx[j], acck[i][j]);
        accv[i][j] = MFMA16(av[i], bx[j], accv[i][j]);
      }
  }

#pragma unroll
  for (int i = 0; i < 2; ++i)
#pragma unroll
    for (int j = 0; j < 2; ++j)
#pragma unroll
      for (int r = 0; r < 4; ++r) {
        const size_t row = (size_t)b * 256 + kk0 + wr + i * 16 + lg * 4 + r;
        const int col = dd0 + wc + j * 16 + lr;
        Xk[row * 1024 + col] = (__fp16)acck[i][j][r];
        Xv[row * 1024 + col] = (__fp16)accv[i][j][r];
      }
}

// ---------------------------------------------------------------------------
// Generic small BT-GEMM: C[i][j] (f16) = sum_e A[i][e] * B[j][e], E=1024.
// 64x64 tile, BK=32, both tiles linear global_load_lds.
// grid (Mtiles, Ntiles, batch); per-batch strides bsA/bsB/bsC.
// ---------------------------------------------------------------------------
__global__ __launch_bounds__(256) void bt64(
    const __fp16* __restrict__ A, long long bsA,
    const __fp16* __restrict__ B, long long bsB,
    __fp16* __restrict__ C, int ldC, long long bsC) {
  constexpr int E = 1024;
  __shared__ __fp16 As[64 * 32];
  __shared__ __fp16 Bs[64 * 32];
  const int t = threadIdx.x;
  const int lane = t & 63, w = t >> 6;
  const int lr = lane & 15, lg = lane >> 4;
  const int i0 = blockIdx.x * 64, j0 = blockIdx.y * 64;
  A += (size_t)blockIdx.z * (size_t)bsA;
  B += (size_t)blockIdx.z * (size_t)bsB;
  C += (size_t)blockIdx.z * (size_t)bsC;
  const int wr = (w >> 1) * 32, wc = (w & 1) * 32;

  f32x4 acc[2][2];
#pragma unroll
  for (int i = 0; i < 2; ++i)
#pragma unroll
    for (int j = 0; j < 2; ++j) acc[i][j] = (f32x4){0.f, 0.f, 0.f, 0.f};

  const int grow = t >> 2, gcol = (t & 3) * 8;
  const __fp16* aSrc = A + (size_t)(i0 + grow) * E + gcol;
  const __fp16* bSrc = B + (size_t)(j0 + grow) * E + gcol;

  for (int e0 = 0; e0 < E; e0 += 32) {
    __syncthreads();
    gload_lds16(aSrc + e0, (char*)As + w * 1024);
    gload_lds16(bSrc + e0, (char*)Bs + w * 1024);
    __syncthreads();

    f16x8 af[2], bf[2];
#pragma unroll
    for (int i = 0; i < 2; ++i)
      af[i] = *(const f16x8*)&As[(wr + i * 16 + lr) * 32 + lg * 8];
#pragma unroll
    for (int j = 0; j < 2; ++j)
      bf[j] = *(const f16x8*)&Bs[(wc + j * 16 + lr) * 32 + lg * 8];
#pragma unroll
    for (int i = 0; i < 2; ++i)
#pragma unroll
      for (int j = 0; j < 2; ++j)
        acc[i][j] = MFMA16(af[i], bf[j], acc[i][j]);
  }

#pragma unroll
  for (int i = 0; i < 2; ++i)
#pragma unroll
    for (int j = 0; j < 2; ++j)
#pragma unroll
      for (int r = 0; r < 4; ++r) {
        const int row = i0 + wr + i * 16 + lg * 4 + r;
        const int col = j0 + wc + j * 16 + lr;
        C[(size_t)row * ldC + col] = (__fp16)acc[i][j][r];
      }
}

// ---------------------------------------------------------------------------
// Q-path GEMM: Qh[16384][1024] (f16) = X(f32) . WqT^T, 128x128 tile, BK=32.
// X tile reg-staged (cvt f32->f16) with 16B-block XOR swizzle (4-way max).
// WqT tile: linear global_load_lds. 4 waves 2x2, 64x64/wave = 4x4 frags.
// ---------------------------------------------------------------------------
__global__ __launch_bounds__(256) void gemm_q(
    const float* __restrict__ X,
    const __fp16* __restrict__ WT,   // [1024][1024], WT[n][k] = W[k][n]
    __fp16* __restrict__ Q) {
  constexpr int K = 1024, N = 1024;
  __shared__ __fp16 Xs[128 * 32];  // [m][k], XOR-swizzled 16B blocks
  __shared__ __fp16 Ws[128 * 32];  // [n][k], linear
  const int t = threadIdx.x;
  const int lane = t & 63, w = t >> 6;
  const int lr = lane & 15, lg = lane >> 4;
  const int m0 = blockIdx.x * 128, n0 = blockIdx.y * 128;
  const int wr = (w >> 1) * 64, wc = (w & 1) * 64;

  f32x4 acc[4][4];
#pragma unroll
  for (int i = 0; i < 4; ++i)
#pragma unroll
    for (int j = 0; j < 4; ++j) acc[i][j] = (f32x4){0.f, 0.f, 0.f, 0.f};

  const int xr = t >> 1, xb = (t & 1) * 2;  // row, first 16B block (of 4)
  const int grow = t >> 2, gcol = (t & 3) * 8;
  const float* xSrc = X + (size_t)(m0 + xr) * K + xb * 8;
  const __fp16* wSrc0 = WT + (size_t)(n0 + grow) * K + gcol;
  const __fp16* wSrc1 = WT + (size_t)(n0 + 64 + grow) * K + gcol;

  for (int k0 = 0; k0 < K; k0 += 32) {
    fl4 x0 = *(const fl4*)(xSrc + k0);
    fl4 x1 = *(const fl4*)(xSrc + k0 + 4);
    fl4 x2 = *(const fl4*)(xSrc + k0 + 8);
    fl4 x3 = *(const fl4*)(xSrc + k0 + 12);
    __syncthreads();
    gload_lds16(wSrc0 + k0, (char*)Ws + w * 1024);
    gload_lds16(wSrc1 + k0, (char*)Ws + 4096 + w * 1024);
    {
      const int s = xr & 3;
      *(f16x8*)&Xs[xr * 32 + ((xb ^ s) * 8)] = pk8(x0, x1);
      *(f16x8*)&Xs[xr * 32 + (((xb + 1) ^ s) * 8)] = pk8(x2, x3);
    }
    __syncthreads();

    f16x8 af[4], bf[4];
#pragma unroll
    for (int i = 0; i < 4; ++i) {
      const int row = wr + i * 16 + lr;
      af[i] = *(const f16x8*)&Xs[row * 32 + ((lg ^ (row & 3)) * 8)];
    }
#pragma unroll
    for (int j = 0; j < 4; ++j)
      bf[j] = *(const f16x8*)&Ws[(wc + j * 16 + lr) * 32 + lg * 8];
#pragma unroll
    for (int i = 0; i < 4; ++i)
#pragma unroll
      for (int j = 0; j < 4; ++j)
        acc[i][j] = MFMA16(af[i], bf[j], acc[i][j]);
  }

#pragma unroll
  for (int i = 0; i < 4; ++i)
#pragma unroll
    for (int j = 0; j < 4; ++j)
#pragma unroll
      for (int r = 0; r < 4; ++r) {
        const int row = m0 + wr + i * 16 + lg * 4 + r;
        const int col = n0 + wc + j * 16 + lr;
        Q[(size_t)row * N + col] = (__fp16)acc[i][j][r];
      }
}

// ---------------------------------------------------------------------------
// Attention: one wave = one 16-row Q strip of one (b,h).  (unchanged, passes)
// ---------------------------------------------------------------------------
__global__ __launch_bounds__(256) void attn_k(
    const __fp16* __restrict__ Q,    // [b*4096][1024]
    const __fp16* __restrict__ Kp,   // [b][256][1024]
    const __fp16* __restrict__ Vpt,  // [b][1024][256]
    float* __restrict__ O) {         // [b*4096][1024] f32
  __shared__ __fp16 P[4][16 * 264];
  const int t = threadIdx.x;
  const int lane = t & 63, w = t >> 6;
  const int lr = lane & 15, lg = lane >> 4;
  const int bh = blockIdx.x >> 6;
  const int sg = blockIdx.x & 63;
  const int b = bh >> 4, h = bh & 15;
  const int m0 = (sg * 4 + w) * 16;

  const __fp16* Qh = Q + ((size_t)(b * 4096 + m0)) * 1024 + h * 64;
  const __fp16* Kph = Kp + (size_t)b * 256 * 1024 + h * 64;
  const __fp16* Vph = Vpt + ((size_t)b * 1024 + h * 64) * 256;

  f16x8 aq0 = *(const f16x8*)(Qh + (size_t)lr * 1024 + lg * 8);
  f16x8 aq1 = *(const f16x8*)(Qh + (size_t)lr * 1024 + 32 + lg * 8);

  f32x4 dots[16];
#pragma unroll
  for (int jt = 0; jt < 16; ++jt) {
    f16x8 k0 = *(const f16x8*)(Kph + (size_t)(jt * 16 + lr) * 1024 + lg * 8);
    f16x8 k1 = *(const f16x8*)(Kph + (size_t)(jt * 16 + lr) * 1024 + 32 + lg * 8);
    f32x4 d = (f32x4){0.f, 0.f, 0.f, 0.f};
    d = MFMA16(aq0, k0, d);
    d = MFMA16(aq1, k1, d);
    dots[jt] = d;
  }

  float mx[4], sm[4];
#pragma unroll
  for (int r = 0; r < 4; ++r) mx[r] = -1e30f;
#pragma unroll
  for (int jt = 0; jt < 16; ++jt)
#pragma unroll
    for (int r = 0; r < 4; ++r) mx[r] = fmaxf(mx[r], dots[jt][r]);
#pragma unroll
  for (int msk = 1; msk <= 8; msk <<= 1)
#pragma unroll
    for (int r = 0; r < 4; ++r) mx[r] = fmaxf(mx[r], __shfl_xor(mx[r], msk, 64));
#pragma unroll
  for (int r = 0; r < 4; ++r) sm[r] = 0.f;
#pragma unroll
  for (int jt = 0; jt < 16; ++jt)
#pragma unroll
    for (int r = 0; r < 4; ++r) {
      float p = __expf(dots[jt][r] - mx[r]);
      dots[jt][r] = p;
      sm[r] += p;
    }
#pragma unroll
  for (int msk = 1; msk <= 8; msk <<= 1)
#pragma unroll
    for (int r = 0; r < 4; ++r) sm[r] += __shfl_xor(sm[r], msk, 64);

  __fp16* Pw = &P[w][0];
#pragma unroll
  for (int jt = 0; jt < 16; ++jt)
#pragma unroll
    for (int r = 0; r < 4; ++r)
      Pw[(lg * 4 + r) * 264 + jt * 16 + lr] = (__fp16)dots[jt][r];
  __syncthreads();

  f32x4 o[4];
#pragma unroll
  for (int j = 0; j < 4; ++j) o[j] = (f32x4){0.f, 0.f, 0.f, 0.f};
#pragma unroll
  for (int ks = 0; ks < 8; ++ks) {
    f16x8 pa = *(const f16x8*)&Pw[lr * 264 + ks * 32 + lg * 8];
#pragma unroll
    for (int jt2 = 0; jt2 < 4; ++jt2) {
      f16x8 bv = *(const f16x8*)(Vph + (size_t)(jt2 * 16 + lr) * 256 + ks * 32 + lg * 8);
      o[jt2] = MFMA16(pa, bv, o[jt2]);
    }
  }

  float rs[4];
#pragma unroll
  for (int r = 0; r < 4; ++r) rs[r] = 1.f / sm[r];
#pragma unroll
  for (int jt2 = 0; jt2 < 4; ++jt2)
#pragma unroll
    for (int r = 0; r < 4; ++r) {
      const size_t row = (size_t)(b * 4096 + m0 + lg * 4 + r);
      O[row * 1024 + h * 64 + jt2 * 16 + lr] = o[jt2][r] * rs[r];
    }
}

// ---------------------------------------------------------------------------
extern "C" void kernel_launch(void* const* d_in, const int* in_sizes, int n_in,
                              void* d_out, int out_size, void* d_ws, size_t ws_size,
                              hipStream_t stream) {
  (void)in_sizes; (void)n_in; (void)out_size; (void)ws_size;
  const float* x  = (const float*)d_in[0];
  const float* Wq = (const float*)d_in[1];
  const float* Wk = (const float*)d_in[2];
  const float* Wv = (const float*)d_in[3];
  const float* pk = (const float*)d_in[4];
  const float* pv = (const float*)d_in[5];
  float* out = (float*)d_out;

  // ws layout (f16 halfwords), total ~52.4 MB
  __fp16* Qh  = (__fp16*)d_ws;                       // 16384*1024
  __fp16* WqT = Qh  + (size_t)16384 * 1024;          // 1024*1024 each
  __fp16* WkT = WqT + (size_t)1024 * 1024;
  __fp16* WvT = WkT + (size_t)1024 * 1024;
  __fp16* pkT = WvT + (size_t)1024 * 1024;           // 256*4096 each
  __fp16* pvT = pkT + (size_t)256 * 4096;
  __fp16* Xk  = pvT + (size_t)256 * 4096;            // 4*256*1024 each
  __fp16* Xv  = Xk  + (size_t)4 * 256 * 1024;
  __fp16* Kp  = Xv  + (size_t)4 * 256 * 1024;
  __fp16* Vpt = Kp  + (size_t)4 * 256 * 1024;

  const dim3 bb(256);

  // 0. one-time transposes (f32 -> f16)
  tr_cvt<<<dim3(32, 32), bb, 0, stream>>>(Wq, WqT, 1024, 1024);
  tr_cvt<<<dim3(32, 32), bb, 0, stream>>>(Wk, WkT, 1024, 1024);
  tr_cvt<<<dim3(32, 32), bb, 0, stream>>>(Wv, WvT, 1024, 1024);
  tr_cvt<<<dim3(8, 128), bb, 0, stream>>>(pk, pkT, 4096, 256);
  tr_cvt<<<dim3(8, 128), bb, 0, stream>>>(pv, pvT, 4096, 256);

  // 1. fused low-rank projections of X
  stage1<<<dim3(4, 16, 4), bb, 0, stream>>>(pkT, pvT, x, Xk, Xv);

  // 2. Kp = Xk . Wk ; VpT = (Xv . Wv)^T
  bt64<<<dim3(4, 16, 4), bb, 0, stream>>>(Xk, 256LL * 1024, WkT, 0LL,
                                          Kp, 1024, 256LL * 1024);
  bt64<<<dim3(16, 4, 4), bb, 0, stream>>>(WvT, 0LL, Xv, 256LL * 1024,
                                          Vpt, 256, 1024LL * 256);

  // 3. Q projection (full size)
  gemm_q<<<dim3(128, 8), bb, 0, stream>>>(x, WqT, Qh);

  // 4. attention
  attn_k<<<dim3(4096), bb, 0, stream>>>(Qh, Kp, Vpt, out);
}

// Round 5
// 261.402 us; speedup vs baseline: 2.5243x; 1.2373x over previous
//
#include <hip/hip_runtime.h>

// ---------------------------------------------------------------------------
// Linformer self-attention, fp32 I/O, fp16 MFMA internally, MI355X (gfx950)
// b=4 n=4096 d=1024 h=16 dh=64 k=256  (no 1/sqrt(dh) scale per reference)
//
// Key algebra: proj_k^T (X Wk) == (proj_k^T X) Wk  -> K/V paths cost 4x less.
// Pipeline:
//   0. tr_cvt   : W^T, pk^T, pv^T  (f32 -> f16, one-time)
//   1. stage1   : Xk[b,256,1024] = pkT . X ; Xv = pvT . X   (fused)
//   2. bt64     : Kp[b,256,1024] = Xk . WkT^T ; VpT[b,1024,256] = WvT . Xv^T
//   3. gemm_q   : Qh[16384,1024] = X . WqT^T   (128x128, global_load_lds B-side)
//   4. attn_k   : LDS-staged K/V per block, 32 Q-rows/wave, in-reg softmax,
//                 P transposed through (reused) K-LDS.
// ---------------------------------------------------------------------------

typedef __fp16 f16x8 __attribute__((ext_vector_type(8)));
typedef __fp16 f16x2 __attribute__((ext_vector_type(2)));
typedef float fl4 __attribute__((ext_vector_type(4)));
typedef float f32x4 __attribute__((ext_vector_type(4)));
typedef unsigned int u32x2 __attribute__((ext_vector_type(2)));

#define MFMA16(a, b, c) __builtin_amdgcn_mfma_f32_16x16x32_f16((a), (b), (c), 0, 0, 0)

__device__ __forceinline__ unsigned int pk2u(float a, float b) {
  f16x2 p = __builtin_amdgcn_cvt_pkrtz(a, b);  // low = a, high = b
  return __builtin_bit_cast(unsigned int, p);
}

__device__ __forceinline__ f16x8 pk8(fl4 a, fl4 b) {
  f16x2 p0 = __builtin_amdgcn_cvt_pkrtz(a[0], a[1]);
  f16x2 p1 = __builtin_amdgcn_cvt_pkrtz(a[2], a[3]);
  f16x2 p2 = __builtin_amdgcn_cvt_pkrtz(b[0], b[1]);
  f16x2 p3 = __builtin_amdgcn_cvt_pkrtz(b[2], b[3]);
  f16x8 r;
  r[0] = p0[0]; r[1] = p0[1]; r[2] = p1[0]; r[3] = p1[1];
  r[4] = p2[0]; r[5] = p2[1]; r[6] = p3[0]; r[7] = p3[1];
  return r;
}

__device__ __forceinline__ void gload_lds16(const __fp16* g, void* lds_base) {
  __builtin_amdgcn_global_load_lds(
      (const __attribute__((address_space(1))) void*)g,
      (__attribute__((address_space(3))) void*)lds_base, 16, 0, 0);
}

// ---------------------------------------------------------------------------
// Transpose + convert: in f32 [R][C] -> out f16 [C][R]. 32x32 tiles.
// ---------------------------------------------------------------------------
__global__ __launch_bounds__(256) void tr_cvt(
    const float* __restrict__ in, __fp16* __restrict__ out, int R, int C) {
  __shared__ float tile[32][33];
  const int t = threadIdx.x;
  const int c0 = blockIdx.x * 32, r0 = blockIdx.y * 32;
  {
    const int r = t >> 3, cg = (t & 7) * 4;
    fl4 v = *(const fl4*)(in + (size_t)(r0 + r) * C + c0 + cg);
    tile[r][cg] = v[0]; tile[r][cg + 1] = v[1];
    tile[r][cg + 2] = v[2]; tile[r][cg + 3] = v[3];
  }
  __syncthreads();
  {
    const int cc = t >> 3, rg = (t & 7) * 4;
    u32x2 p;
    p[0] = pk2u(tile[rg + 0][cc], tile[rg + 1][cc]);
    p[1] = pk2u(tile[rg + 2][cc], tile[rg + 3][cc]);
    *(u32x2*)(out + (size_t)(c0 + cc) * R + r0 + rg) = p;
  }
}

// ---------------------------------------------------------------------------
// Stage 1 (fused K+V): Xk[b][kk][dd] = sum_n pkT[kk][n] * X[b][n][dd]; Xv likewise.
// ---------------------------------------------------------------------------
__global__ __launch_bounds__(256) void stage1(
    const __fp16* __restrict__ pkT,  // [256][4096]
    const __fp16* __restrict__ pvT,  // [256][4096]
    const float* __restrict__ X,     // [b][4096][1024]
    __fp16* __restrict__ Xk,         // [b][256][1024]
    __fp16* __restrict__ Xv) {       // [b][256][1024]
  __shared__ __fp16 Ak[64 * 32];
  __shared__ __fp16 Av[64 * 32];
  __shared__ __fp16 Bt[64 * 32];  // [dd][n], XOR-swizzled 16B blocks
  const int t = threadIdx.x;
  const int lane = t & 63, w = t >> 6;
  const int lr = lane & 15, lg = lane >> 4;
  const int kk0 = blockIdx.x * 64, dd0 = blockIdx.y * 64;
  const int b = blockIdx.z;
  const int wr = (w >> 1) * 32, wc = (w & 1) * 32;

  f32x4 acck[2][2], accv[2][2];
#pragma unroll
  for (int i = 0; i < 2; ++i)
#pragma unroll
    for (int j = 0; j < 2; ++j) {
      acck[i][j] = (f32x4){0.f, 0.f, 0.f, 0.f};
      accv[i][j] = (f32x4){0.f, 0.f, 0.f, 0.f};
    }

  const int grow = t >> 2, gcol = (t & 3) * 8;      // gload indices
  const int np = t >> 4, ddl = (t & 15) * 4;        // X^T staging indices
  const __fp16* pkSrc = pkT + (size_t)(kk0 + grow) * 4096 + gcol;
  const __fp16* pvSrc = pvT + (size_t)(kk0 + grow) * 4096 + gcol;
  const float* xSrc = X + ((size_t)b * 4096 + 2 * np) * 1024 + dd0 + ddl;

  for (int n0 = 0; n0 < 4096; n0 += 32) {
    fl4 x0 = *(const fl4*)(xSrc + (size_t)n0 * 1024);
    fl4 x1 = *(const fl4*)(xSrc + (size_t)(n0 + 1) * 1024);
    __syncthreads();
    gload_lds16(pkSrc + n0, (char*)Ak + w * 1024);
    gload_lds16(pvSrc + n0, (char*)Av + w * 1024);
#pragma unroll
    for (int j = 0; j < 4; ++j) {
      const int dd = ddl + j;
      const int slot = (((np >> 2) ^ ((dd >> 3) & 3)) << 2) + (np & 3);
      *(unsigned int*)&Bt[dd * 32 + slot * 2] = pk2u(x0[j], x1[j]);
    }
    __syncthreads();

    f16x8 ak[2], av[2], bx[2];
#pragma unroll
    for (int i = 0; i < 2; ++i) {
      ak[i] = *(const f16x8*)&Ak[(wr + i * 16 + lr) * 32 + lg * 8];
      av[i] = *(const f16x8*)&Av[(wr + i * 16 + lr) * 32 + lg * 8];
    }
#pragma unroll
    for (int j = 0; j < 2; ++j) {
      const int dd = wc + j * 16 + lr;
      bx[j] = *(const f16x8*)&Bt[dd * 32 + ((lg ^ ((dd >> 3) & 3)) * 8)];
    }
#pragma unroll
    for (int i = 0; i < 2; ++i)
#pragma unroll
      for (int j = 0; j < 2; ++j) {
        acck[i][j] = MFMA16(ak[i], bx[j], acck[i][j]);
        accv[i][j] = MFMA16(av[i], bx[j], accv[i][j]);
      }
  }

#pragma unroll
  for (int i = 0; i < 2; ++i)
#pragma unroll
    for (int j = 0; j < 2; ++j)
#pragma unroll
      for (int r = 0; r < 4; ++r) {
        const size_t row = (size_t)b * 256 + kk0 + wr + i * 16 + lg * 4 + r;
        const int col = dd0 + wc + j * 16 + lr;
        Xk[row * 1024 + col] = (__fp16)acck[i][j][r];
        Xv[row * 1024 + col] = (__fp16)accv[i][j][r];
      }
}

// ---------------------------------------------------------------------------
// Generic small BT-GEMM: C[i][j] (f16) = sum_e A[i][e] * B[j][e], E=1024.
// ---------------------------------------------------------------------------
__global__ __launch_bounds__(256) void bt64(
    const __fp16* __restrict__ A, long long bsA,
    const __fp16* __restrict__ B, long long bsB,
    __fp16* __restrict__ C, int ldC, long long bsC) {
  constexpr int E = 1024;
  __shared__ __fp16 As[64 * 32];
  __shared__ __fp16 Bs[64 * 32];
  const int t = threadIdx.x;
  const int lane = t & 63, w = t >> 6;
  const int lr = lane & 15, lg = lane >> 4;
  const int i0 = blockIdx.x * 64, j0 = blockIdx.y * 64;
  A += (size_t)blockIdx.z * (size_t)bsA;
  B += (size_t)blockIdx.z * (size_t)bsB;
  C += (size_t)blockIdx.z * (size_t)bsC;
  const int wr = (w >> 1) * 32, wc = (w & 1) * 32;

  f32x4 acc[2][2];
#pragma unroll
  for (int i = 0; i < 2; ++i)
#pragma unroll
    for (int j = 0; j < 2; ++j) acc[i][j] = (f32x4){0.f, 0.f, 0.f, 0.f};

  const int grow = t >> 2, gcol = (t & 3) * 8;
  const __fp16* aSrc = A + (size_t)(i0 + grow) * E + gcol;
  const __fp16* bSrc = B + (size_t)(j0 + grow) * E + gcol;

  for (int e0 = 0; e0 < E; e0 += 32) {
    __syncthreads();
    gload_lds16(aSrc + e0, (char*)As + w * 1024);
    gload_lds16(bSrc + e0, (char*)Bs + w * 1024);
    __syncthreads();

    f16x8 af[2], bf[2];
#pragma unroll
    for (int i = 0; i < 2; ++i)
      af[i] = *(const f16x8*)&As[(wr + i * 16 + lr) * 32 + lg * 8];
#pragma unroll
    for (int j = 0; j < 2; ++j)
      bf[j] = *(const f16x8*)&Bs[(wc + j * 16 + lr) * 32 + lg * 8];
#pragma unroll
    for (int i = 0; i < 2; ++i)
#pragma unroll
      for (int j = 0; j < 2; ++j)
        acc[i][j] = MFMA16(af[i], bf[j], acc[i][j]);
  }

#pragma unroll
  for (int i = 0; i < 2; ++i)
#pragma unroll
    for (int j = 0; j < 2; ++j)
#pragma unroll
      for (int r = 0; r < 4; ++r) {
        const int row = i0 + wr + i * 16 + lg * 4 + r;
        const int col = j0 + wc + j * 16 + lr;
        C[(size_t)row * ldC + col] = (__fp16)acc[i][j][r];
      }
}

// ---------------------------------------------------------------------------
// Q-path GEMM: Qh[16384][1024] (f16) = X(f32) . WqT^T, 128x128 tile, BK=32.
// ---------------------------------------------------------------------------
__global__ __launch_bounds__(256) void gemm_q(
    const float* __restrict__ X,
    const __fp16* __restrict__ WT,   // [1024][1024], WT[n][k] = W[k][n]
    __fp16* __restrict__ Q) {
  constexpr int K = 1024, N = 1024;
  __shared__ __fp16 Xs[128 * 32];  // [m][k], XOR-swizzled 16B blocks
  __shared__ __fp16 Ws[128 * 32];  // [n][k], linear
  const int t = threadIdx.x;
  const int lane = t & 63, w = t >> 6;
  const int lr = lane & 15, lg = lane >> 4;
  const int m0 = blockIdx.x * 128, n0 = blockIdx.y * 128;
  const int wr = (w >> 1) * 64, wc = (w & 1) * 64;

  f32x4 acc[4][4];
#pragma unroll
  for (int i = 0; i < 4; ++i)
#pragma unroll
    for (int j = 0; j < 4; ++j) acc[i][j] = (f32x4){0.f, 0.f, 0.f, 0.f};

  const int xr = t >> 1, xb = (t & 1) * 2;
  const int grow = t >> 2, gcol = (t & 3) * 8;
  const float* xSrc = X + (size_t)(m0 + xr) * K + xb * 8;
  const __fp16* wSrc0 = WT + (size_t)(n0 + grow) * K + gcol;
  const __fp16* wSrc1 = WT + (size_t)(n0 + 64 + grow) * K + gcol;

  for (int k0 = 0; k0 < K; k0 += 32) {
    fl4 x0 = *(const fl4*)(xSrc + k0);
    fl4 x1 = *(const fl4*)(xSrc + k0 + 4);
    fl4 x2 = *(const fl4*)(xSrc + k0 + 8);
    fl4 x3 = *(const fl4*)(xSrc + k0 + 12);
    __syncthreads();
    gload_lds16(wSrc0 + k0, (char*)Ws + w * 1024);
    gload_lds16(wSrc1 + k0, (char*)Ws + 4096 + w * 1024);
    {
      const int s = xr & 3;
      *(f16x8*)&Xs[xr * 32 + ((xb ^ s) * 8)] = pk8(x0, x1);
      *(f16x8*)&Xs[xr * 32 + (((xb + 1) ^ s) * 8)] = pk8(x2, x3);
    }
    __syncthreads();

    f16x8 af[4], bf[4];
#pragma unroll
    for (int i = 0; i < 4; ++i) {
      const int row = wr + i * 16 + lr;
      af[i] = *(const f16x8*)&Xs[row * 32 + ((lg ^ (row & 3)) * 8)];
    }
#pragma unroll
    for (int j = 0; j < 4; ++j)
      bf[j] = *(const f16x8*)&Ws[(wc + j * 16 + lr) * 32 + lg * 8];
#pragma unroll
    for (int i = 0; i < 4; ++i)
#pragma unroll
      for (int j = 0; j < 4; ++j)
        acc[i][j] = MFMA16(af[i], bf[j], acc[i][j]);
  }

#pragma unroll
  for (int i = 0; i < 4; ++i)
#pragma unroll
    for (int j = 0; j < 4; ++j)
#pragma unroll
      for (int r = 0; r < 4; ++r) {
        const int row = m0 + wr + i * 16 + lg * 4 + r;
        const int col = n0 + wc + j * 16 + lr;
        Q[(size_t)row * N + col] = (__fp16)acc[i][j][r];
      }
}

// ---------------------------------------------------------------------------
// Attention (rewritten): block = 4 waves, 128 Q-rows of one (b,h); grid 2048.
// K_h (256x64) and V_h^T (64x256) staged once into LDS via global_load_lds
// with source-side chunk swizzle (chunk ^= row&7) so swizzled ds_read_b128
// fragment reads are conflict-free. Each wave: 32 rows; dots in 128 VGPR;
// in-reg softmax (16-lane shfl groups); P transposed through the (dead)
// K-LDS region in two 16-row halves; PV from LDS.
// ---------------------------------------------------------------------------
__global__ __launch_bounds__(256) void attn_k(
    const __fp16* __restrict__ Q,    // [b*4096][1024]
    const __fp16* __restrict__ Kp,   // [b][256][1024]
    const __fp16* __restrict__ Vpt,  // [b][1024][256]
    float* __restrict__ O) {         // [b*4096][1024] f32
  __shared__ __fp16 Ks[256 * 64];    // 32KB: K tiles; reused as P (8KB/wave)
  __shared__ __fp16 Vs[64 * 256];    // 32KB: V^T tiles
  const int t = threadIdx.x;
  const int lane = t & 63, w = t >> 6;
  const int lr = lane & 15, lg = lane >> 4;
  const int bh = blockIdx.x >> 5, rb = blockIdx.x & 31;
  const int b = bh >> 4, h = bh & 15;
  const int m0 = rb * 128 + w * 32;

  const __fp16* Kph = Kp + (size_t)b * 256 * 1024 + h * 64;
  const __fp16* Vph = Vpt + ((size_t)b * 1024 + h * 64) * 256;
  const __fp16* Qh = Q + ((size_t)(b * 4096 + m0)) * 1024 + h * 64;

  // ---- stage K: LDS[kk][chunk] holds K[kk][(chunk^(kk&7))*8..] (linear dest)
#pragma unroll
  for (int i = 0; i < 8; ++i) {
    const int kr = (i * 4 + w) * 8 + (lane >> 3);
    gload_lds16(Kph + (size_t)kr * 1024 + (((lane & 7) ^ (kr & 7)) * 8),
                (char*)Ks + (i * 4 + w) * 1024);
  }
  // ---- stage V^T: LDS[dd][chunk] holds V^T[dd][(chunk^(dd&7))*8..]
#pragma unroll
  for (int i = 0; i < 8; ++i) {
    const int dd = (i * 4 + w) * 2 + (lane >> 5);
    gload_lds16(Vph + (size_t)dd * 256 + (((lane & 31) ^ (dd & 7)) * 8),
                (char*)Vs + (i * 4 + w) * 1024);
  }

  // Q A-fragments for this wave's 32 rows (2 row-tiles x 2 k-steps)
  f16x8 aq[2][2];
#pragma unroll
  for (int mi = 0; mi < 2; ++mi)
#pragma unroll
    for (int s = 0; s < 2; ++s)
      aq[mi][s] =
          *(const f16x8*)(Qh + (size_t)(mi * 16 + lr) * 1024 + s * 32 + lg * 8);

  __syncthreads();  // staging complete (barrier drains vmcnt)

  // ---- QK^T: dots[mi][jt], D-layout row = lg*4+r, col = jt*16+lr
  f32x4 dots[2][16];
#pragma unroll
  for (int mi = 0; mi < 2; ++mi)
#pragma unroll
    for (int jt = 0; jt < 16; ++jt) dots[mi][jt] = (f32x4){0.f, 0.f, 0.f, 0.f};
#pragma unroll
  for (int jt = 0; jt < 16; ++jt) {
    const int r = jt * 16 + lr;
    f16x8 k0 = *(const f16x8*)((const char*)Ks + r * 128 + ((lg ^ (r & 7)) * 16));
    f16x8 k1 =
        *(const f16x8*)((const char*)Ks + r * 128 + (((4 + lg) ^ (r & 7)) * 16));
    dots[0][jt] = MFMA16(aq[0][0], k0, dots[0][jt]);
    dots[0][jt] = MFMA16(aq[0][1], k1, dots[0][jt]);
    dots[1][jt] = MFMA16(aq[1][0], k0, dots[1][jt]);
    dots[1][jt] = MFMA16(aq[1][1], k1, dots[1][jt]);
  }

  // ---- softmax (per mi, per r): reduce over jt in-reg, over lr via shfl
  float mx[2][4], sm[2][4];
#pragma unroll
  for (int mi = 0; mi < 2; ++mi) {
#pragma unroll
    for (int r = 0; r < 4; ++r) mx[mi][r] = -1e30f;
#pragma unroll
    for (int jt = 0; jt < 16; ++jt)
#pragma unroll
      for (int r = 0; r < 4; ++r) mx[mi][r] = fmaxf(mx[mi][r], dots[mi][jt][r]);
#pragma unroll
    for (int msk = 1; msk <= 8; msk <<= 1)
#pragma unroll
      for (int r = 0; r < 4; ++r)
        mx[mi][r] = fmaxf(mx[mi][r], __shfl_xor(mx[mi][r], msk, 64));
#pragma unroll
    for (int r = 0; r < 4; ++r) sm[mi][r] = 0.f;
#pragma unroll
    for (int jt = 0; jt < 16; ++jt)
#pragma unroll
      for (int r = 0; r < 4; ++r) {
        float p = __expf(dots[mi][jt][r] - mx[mi][r]);
        dots[mi][jt][r] = p;
        sm[mi][r] += p;
      }
#pragma unroll
    for (int msk = 1; msk <= 8; msk <<= 1)
#pragma unroll
      for (int r = 0; r < 4; ++r) sm[mi][r] += __shfl_xor(sm[mi][r], msk, 64);
  }

  __syncthreads();  // all waves done reading Ks -> safe to reuse as P

  // ---- per half: P -> LDS (swizzled transpose), then PV from LDS
  char* Pw = (char*)Ks + w * 8192;  // 16 rows x 512B
#pragma unroll
  for (int mi = 0; mi < 2; ++mi) {
#pragma unroll
    for (int jt = 0; jt < 16; ++jt)
#pragma unroll
      for (int r = 0; r < 4; ++r) {
        const int m = lg * 4 + r;
        const int ch = (2 * jt + (lr >> 3)) ^ (m & 7);
        *(__fp16*)(Pw + m * 512 + ch * 16 + (lr & 7) * 2) =
            (__fp16)dots[mi][jt][r];
      }

    f32x4 o[4];
#pragma unroll
    for (int j = 0; j < 4; ++j) o[j] = (f32x4){0.f, 0.f, 0.f, 0.f};
#pragma unroll
    for (int ks = 0; ks < 8; ++ks) {
      f16x8 pa =
          *(const f16x8*)(Pw + lr * 512 + (((ks * 4 + lg) ^ (lr & 7)) * 16));
#pragma unroll
      for (int jt2 = 0; jt2 < 4; ++jt2) {
        const int dd = jt2 * 16 + lr;
        f16x8 bv = *(const f16x8*)((const char*)Vs + dd * 512 +
                                   (((ks * 4 + lg) ^ (dd & 7)) * 16));
        o[jt2] = MFMA16(pa, bv, o[jt2]);
      }
    }

#pragma unroll
    for (int jt2 = 0; jt2 < 4; ++jt2)
#pragma unroll
      for (int r = 0; r < 4; ++r) {
        const size_t row = (size_t)(b * 4096 + m0 + mi * 16 + lg * 4 + r);
        O[row * 1024 + h * 64 + jt2 * 16 + lr] = o[jt2][r] / sm[mi][r];
      }
  }
}

// ---------------------------------------------------------------------------
extern "C" void kernel_launch(void* const* d_in, const int* in_sizes, int n_in,
                              void* d_out, int out_size, void* d_ws, size_t ws_size,
                              hipStream_t stream) {
  (void)in_sizes; (void)n_in; (void)out_size; (void)ws_size;
  const float* x  = (const float*)d_in[0];
  const float* Wq = (const float*)d_in[1];
  const float* Wk = (const float*)d_in[2];
  const float* Wv = (const float*)d_in[3];
  const float* pk = (const float*)d_in[4];
  const float* pv = (const float*)d_in[5];
  float* out = (float*)d_out;

  // ws layout (f16 halfwords), total ~52.4 MB
  __fp16* Qh  = (__fp16*)d_ws;                       // 16384*1024
  __fp16* WqT = Qh  + (size_t)16384 * 1024;          // 1024*1024 each
  __fp16* WkT = WqT + (size_t)1024 * 1024;
  __fp16* WvT = WkT + (size_t)1024 * 1024;
  __fp16* pkT = WvT + (size_t)1024 * 1024;           // 256*4096 each
  __fp16* pvT = pkT + (size_t)256 * 4096;
  __fp16* Xk  = pvT + (size_t)256 * 4096;            // 4*256*1024 each
  __fp16* Xv  = Xk  + (size_t)4 * 256 * 1024;
  __fp16* Kp  = Xv  + (size_t)4 * 256 * 1024;
  __fp16* Vpt = Kp  + (size_t)4 * 256 * 1024;

  const dim3 bb(256);

  // 0. one-time transposes (f32 -> f16)
  tr_cvt<<<dim3(32, 32), bb, 0, stream>>>(Wq, WqT, 1024, 1024);
  tr_cvt<<<dim3(32, 32), bb, 0, stream>>>(Wk, WkT, 1024, 1024);
  tr_cvt<<<dim3(32, 32), bb, 0, stream>>>(Wv, WvT, 1024, 1024);
  tr_cvt<<<dim3(8, 128), bb, 0, stream>>>(pk, pkT, 4096, 256);
  tr_cvt<<<dim3(8, 128), bb, 0, stream>>>(pv, pvT, 4096, 256);

  // 1. fused low-rank projections of X
  stage1<<<dim3(4, 16, 4), bb, 0, stream>>>(pkT, pvT, x, Xk, Xv);

  // 2. Kp = Xk . Wk ; VpT = (Xv . Wv)^T
  bt64<<<dim3(4, 16, 4), bb, 0, stream>>>(Xk, 256LL * 1024, WkT, 0LL,
                                          Kp, 1024, 256LL * 1024);
  bt64<<<dim3(16, 4, 4), bb, 0, stream>>>(WvT, 0LL, Xv, 256LL * 1024,
                                          Vpt, 256, 1024LL * 256);

  // 3. Q projection (full size)
  gemm_q<<<dim3(128, 8), bb, 0, stream>>>(x, WqT, Qh);

  // 4. attention (LDS-staged K/V)
  attn_k<<<dim3(2048), bb, 0, stream>>>(Qh, Kp, Vpt, out);
}

// Round 6
// 231.575 us; speedup vs baseline: 2.8494x; 1.1288x over previous
//
#include <hip/hip_runtime.h>

// ---------------------------------------------------------------------------
// Linformer self-attention, fp32 I/O, fp16 MFMA internally, MI355X (gfx950)
// b=4 n=4096 d=1024 h=16 dh=64 k=256  (no 1/sqrt(dh) scale per reference)
//
// Key algebra: proj_k^T (X Wk) == (proj_k^T X) Wk  -> K/V paths cost 4x less.
// Pipeline:
//   0. tr_cvt        : W^T, pk^T, pv^T  (f32 -> f16, one-time)
//   1. stage1_partial: split-K (4 n-chunks) partials of pkT.X / pvT.X  (f32)
//      stage1_reduce : sum 4 partials -> Xk, Xv (f16)   [partials live in Qh region]
//   2. bt64          : Kp = Xk.WkT^T ; VpT = (WvT.Xv^T)
//   3. gemm_q        : Qh = X.WqT^T  (overwrites partials region - after reduce)
//   4. attn_k        : LDS-staged K/V, 32 Q-rows/wave, in-reg softmax
// ---------------------------------------------------------------------------

typedef __fp16 f16x8 __attribute__((ext_vector_type(8)));
typedef __fp16 f16x2 __attribute__((ext_vector_type(2)));
typedef float fl4 __attribute__((ext_vector_type(4)));
typedef float f32x4 __attribute__((ext_vector_type(4)));
typedef unsigned int u32x2 __attribute__((ext_vector_type(2)));

#define MFMA16(a, b, c) __builtin_amdgcn_mfma_f32_16x16x32_f16((a), (b), (c), 0, 0, 0)

__device__ __forceinline__ unsigned int pk2u(float a, float b) {
  f16x2 p = __builtin_amdgcn_cvt_pkrtz(a, b);  // low = a, high = b
  return __builtin_bit_cast(unsigned int, p);
}

__device__ __forceinline__ f16x8 pk8(fl4 a, fl4 b) {
  f16x2 p0 = __builtin_amdgcn_cvt_pkrtz(a[0], a[1]);
  f16x2 p1 = __builtin_amdgcn_cvt_pkrtz(a[2], a[3]);
  f16x2 p2 = __builtin_amdgcn_cvt_pkrtz(b[0], b[1]);
  f16x2 p3 = __builtin_amdgcn_cvt_pkrtz(b[2], b[3]);
  f16x8 r;
  r[0] = p0[0]; r[1] = p0[1]; r[2] = p1[0]; r[3] = p1[1];
  r[4] = p2[0]; r[5] = p2[1]; r[6] = p3[0]; r[7] = p3[1];
  return r;
}

__device__ __forceinline__ void gload_lds16(const __fp16* g, void* lds_base) {
  __builtin_amdgcn_global_load_lds(
      (const __attribute__((address_space(1))) void*)g,
      (__attribute__((address_space(3))) void*)lds_base, 16, 0, 0);
}

// ---------------------------------------------------------------------------
// Transpose + convert: in f32 [R][C] -> out f16 [C][R]. 32x32 tiles.
// ---------------------------------------------------------------------------
__global__ __launch_bounds__(256) void tr_cvt(
    const float* __restrict__ in, __fp16* __restrict__ out, int R, int C) {
  __shared__ float tile[32][33];
  const int t = threadIdx.x;
  const int c0 = blockIdx.x * 32, r0 = blockIdx.y * 32;
  {
    const int r = t >> 3, cg = (t & 7) * 4;
    fl4 v = *(const fl4*)(in + (size_t)(r0 + r) * C + c0 + cg);
    tile[r][cg] = v[0]; tile[r][cg + 1] = v[1];
    tile[r][cg + 2] = v[2]; tile[r][cg + 3] = v[3];
  }
  __syncthreads();
  {
    const int cc = t >> 3, rg = (t & 7) * 4;
    u32x2 p;
    p[0] = pk2u(tile[rg + 0][cc], tile[rg + 1][cc]);
    p[1] = pk2u(tile[rg + 2][cc], tile[rg + 3][cc]);
    *(u32x2*)(out + (size_t)(c0 + cc) * R + r0 + rg) = p;
  }
}

// ---------------------------------------------------------------------------
// Stage 1, split-K partials:
//   Pk[z][kk][dd] = sum_{n in chunk c} pkT[kk][n] * X[b][n][dd]   (z = c*4+b)
//   Pv likewise. Grid (4 kk-tiles, 16 dd-tiles, 16 = chunk*4+batch).
// X^T tile: each thread builds one 16B chunk (8 n x 1 dd) -> ds_write_b128,
// position XOR-swizzled by (dd>>1)&3 -> 2-way max on write AND read.
// ---------------------------------------------------------------------------
__global__ __launch_bounds__(256) void stage1_partial(
    const __fp16* __restrict__ pkT,  // [256][4096]
    const __fp16* __restrict__ pvT,  // [256][4096]
    const float* __restrict__ X,     // [b][4096][1024]
    float* __restrict__ Pk,          // [16][256][1024]
    float* __restrict__ Pv) {        // [16][256][1024]
  __shared__ __fp16 Ak[64 * 32];
  __shared__ __fp16 Av[64 * 32];
  __shared__ __fp16 Bt[64 * 32];  // [dd][n], 64B rows, 16B-chunk XOR swizzle
  const int t = threadIdx.x;
  const int lane = t & 63, w = t >> 6;
  const int lr = lane & 15, lg = lane >> 4;
  const int kk0 = blockIdx.x * 64, dd0 = blockIdx.y * 64;
  const int z = blockIdx.z, b = z & 3, c = z >> 2;
  const int wr = (w >> 1) * 32, wc = (w & 1) * 32;

  f32x4 acck[2][2], accv[2][2];
#pragma unroll
  for (int i = 0; i < 2; ++i)
#pragma unroll
    for (int j = 0; j < 2; ++j) {
      acck[i][j] = (f32x4){0.f, 0.f, 0.f, 0.f};
      accv[i][j] = (f32x4){0.f, 0.f, 0.f, 0.f};
    }

  const int grow = t >> 2, gcol = (t & 3) * 8;  // pkT/pvT gload indices
  const int xdd = t & 63;                        // X staging: 1 dd, octet w
  const int wch = w ^ ((xdd >> 1) & 3);          // swizzled 16B chunk pos
  const __fp16* pkSrc = pkT + (size_t)(kk0 + grow) * 4096 + c * 1024 + gcol;
  const __fp16* pvSrc = pvT + (size_t)(kk0 + grow) * 4096 + c * 1024 + gcol;
  const float* xSrc =
      X + ((size_t)b * 4096 + c * 1024 + w * 8) * 1024 + dd0 + xdd;

  for (int it = 0; it < 32; ++it) {
    const int n0 = it * 32;
    float xv[8];
#pragma unroll
    for (int i = 0; i < 8; ++i) xv[i] = xSrc[(size_t)(n0 + i) * 1024];
    __syncthreads();
    gload_lds16(pkSrc + n0, (char*)Ak + w * 1024);
    gload_lds16(pvSrc + n0, (char*)Av + w * 1024);
    *(f16x8*)((char*)Bt + xdd * 64 + wch * 16) =
        pk8((fl4){xv[0], xv[1], xv[2], xv[3]}, (fl4){xv[4], xv[5], xv[6], xv[7]});
    __syncthreads();

    f16x8 ak[2], av[2], bx[2];
#pragma unroll
    for (int i = 0; i < 2; ++i) {
      ak[i] = *(const f16x8*)&Ak[(wr + i * 16 + lr) * 32 + lg * 8];
      av[i] = *(const f16x8*)&Av[(wr + i * 16 + lr) * 32 + lg * 8];
    }
#pragma unroll
    for (int j = 0; j < 2; ++j) {
      const int dd = wc + j * 16 + lr;
      bx[j] = *(const f16x8*)((const char*)Bt + dd * 64 +
                              ((lg ^ ((dd >> 1) & 3)) * 16));
    }
#pragma unroll
    for (int i = 0; i < 2; ++i)
#pragma unroll
      for (int j = 0; j < 2; ++j) {
        acck[i][j] = MFMA16(ak[i], bx[j], acck[i][j]);
        accv[i][j] = MFMA16(av[i], bx[j], accv[i][j]);
      }
  }

#pragma unroll
  for (int i = 0; i < 2; ++i)
#pragma unroll
    for (int j = 0; j < 2; ++j)
#pragma unroll
      for (int r = 0; r < 4; ++r) {
        const size_t row = (size_t)z * 256 + kk0 + wr + i * 16 + lg * 4 + r;
        const int col = dd0 + wc + j * 16 + lr;
        Pk[row * 1024 + col] = acck[i][j][r];
        Pv[row * 1024 + col] = accv[i][j][r];
      }
}

// ---------------------------------------------------------------------------
// Stage 1 reduce: Xk = f16(sum_c Pk[c*4+b]), Xv likewise. 4 f32/thread.
// ---------------------------------------------------------------------------
__global__ __launch_bounds__(256) void stage1_reduce(
    const float* __restrict__ Pk, const float* __restrict__ Pv,
    __fp16* __restrict__ Xk, __fp16* __restrict__ Xv) {
  const size_t base = ((size_t)blockIdx.x * 256 + threadIdx.x) * 4;
  const int b = (int)(base >> 18);          // 256K elems per batch slab
  const size_t rem = base & 0x3FFFFu;
  fl4 ak = (fl4){0.f, 0.f, 0.f, 0.f}, av = (fl4){0.f, 0.f, 0.f, 0.f};
#pragma unroll
  for (int c = 0; c < 4; ++c) {
    const size_t off = (((size_t)(c * 4 + b)) << 18) + rem;
    ak += *(const fl4*)(Pk + off);
    av += *(const fl4*)(Pv + off);
  }
  u32x2 pkp, pvp;
  pkp[0] = pk2u(ak[0], ak[1]); pkp[1] = pk2u(ak[2], ak[3]);
  pvp[0] = pk2u(av[0], av[1]); pvp[1] = pk2u(av[2], av[3]);
  *(u32x2*)(Xk + base) = pkp;
  *(u32x2*)(Xv + base) = pvp;
}

// ---------------------------------------------------------------------------
// Generic small BT-GEMM: C[i][j] (f16) = sum_e A[i][e] * B[j][e], E=1024.
// ---------------------------------------------------------------------------
__global__ __launch_bounds__(256) void bt64(
    const __fp16* __restrict__ A, long long bsA,
    const __fp16* __restrict__ B, long long bsB,
    __fp16* __restrict__ C, int ldC, long long bsC) {
  constexpr int E = 1024;
  __shared__ __fp16 As[64 * 32];
  __shared__ __fp16 Bs[64 * 32];
  const int t = threadIdx.x;
  const int lane = t & 63, w = t >> 6;
  const int lr = lane & 15, lg = lane >> 4;
  const int i0 = blockIdx.x * 64, j0 = blockIdx.y * 64;
  A += (size_t)blockIdx.z * (size_t)bsA;
  B += (size_t)blockIdx.z * (size_t)bsB;
  C += (size_t)blockIdx.z * (size_t)bsC;
  const int wr = (w >> 1) * 32, wc = (w & 1) * 32;

  f32x4 acc[2][2];
#pragma unroll
  for (int i = 0; i < 2; ++i)
#pragma unroll
    for (int j = 0; j < 2; ++j) acc[i][j] = (f32x4){0.f, 0.f, 0.f, 0.f};

  const int grow = t >> 2, gcol = (t & 3) * 8;
  const __fp16* aSrc = A + (size_t)(i0 + grow) * E + gcol;
  const __fp16* bSrc = B + (size_t)(j0 + grow) * E + gcol;

  for (int e0 = 0; e0 < E; e0 += 32) {
    __syncthreads();
    gload_lds16(aSrc + e0, (char*)As + w * 1024);
    gload_lds16(bSrc + e0, (char*)Bs + w * 1024);
    __syncthreads();

    f16x8 af[2], bf[2];
#pragma unroll
    for (int i = 0; i < 2; ++i)
      af[i] = *(const f16x8*)&As[(wr + i * 16 + lr) * 32 + lg * 8];
#pragma unroll
    for (int j = 0; j < 2; ++j)
      bf[j] = *(const f16x8*)&Bs[(wc + j * 16 + lr) * 32 + lg * 8];
#pragma unroll
    for (int i = 0; i < 2; ++i)
#pragma unroll
      for (int j = 0; j < 2; ++j)
        acc[i][j] = MFMA16(af[i], bf[j], acc[i][j]);
  }

#pragma unroll
  for (int i = 0; i < 2; ++i)
#pragma unroll
    for (int j = 0; j < 2; ++j)
#pragma unroll
      for (int r = 0; r < 4; ++r) {
        const int row = i0 + wr + i * 16 + lg * 4 + r;
        const int col = j0 + wc + j * 16 + lr;
        C[(size_t)row * ldC + col] = (__fp16)acc[i][j][r];
      }
}

// ---------------------------------------------------------------------------
// Q-path GEMM: Qh[16384][1024] (f16) = X(f32) . WqT^T, 128x128 tile, BK=32.
// ---------------------------------------------------------------------------
__global__ __launch_bounds__(256) void gemm_q(
    const float* __restrict__ X,
    const __fp16* __restrict__ WT,   // [1024][1024], WT[n][k] = W[k][n]
    __fp16* __restrict__ Q) {
  constexpr int K = 1024, N = 1024;
  __shared__ __fp16 Xs[128 * 32];  // [m][k], XOR-swizzled 16B blocks
  __shared__ __fp16 Ws[128 * 32];  // [n][k], linear
  const int t = threadIdx.x;
  const int lane = t & 63, w = t >> 6;
  const int lr = lane & 15, lg = lane >> 4;
  const int m0 = blockIdx.x * 128, n0 = blockIdx.y * 128;
  const int wr = (w >> 1) * 64, wc = (w & 1) * 64;

  f32x4 acc[4][4];
#pragma unroll
  for (int i = 0; i < 4; ++i)
#pragma unroll
    for (int j = 0; j < 4; ++j) acc[i][j] = (f32x4){0.f, 0.f, 0.f, 0.f};

  const int xr = t >> 1, xb = (t & 1) * 2;
  const int grow = t >> 2, gcol = (t & 3) * 8;
  const float* xSrc = X + (size_t)(m0 + xr) * K + xb * 8;
  const __fp16* wSrc0 = WT + (size_t)(n0 + grow) * K + gcol;
  const __fp16* wSrc1 = WT + (size_t)(n0 + 64 + grow) * K + gcol;

  for (int k0 = 0; k0 < K; k0 += 32) {
    fl4 x0 = *(const fl4*)(xSrc + k0);
    fl4 x1 = *(const fl4*)(xSrc + k0 + 4);
    fl4 x2 = *(const fl4*)(xSrc + k0 + 8);
    fl4 x3 = *(const fl4*)(xSrc + k0 + 12);
    __syncthreads();
    gload_lds16(wSrc0 + k0, (char*)Ws + w * 1024);
    gload_lds16(wSrc1 + k0, (char*)Ws + 4096 + w * 1024);
    {
      const int s = xr & 3;
      *(f16x8*)&Xs[xr * 32 + ((xb ^ s) * 8)] = pk8(x0, x1);
      *(f16x8*)&Xs[xr * 32 + (((xb + 1) ^ s) * 8)] = pk8(x2, x3);
    }
    __syncthreads();

    f16x8 af[4], bf[4];
#pragma unroll
    for (int i = 0; i < 4; ++i) {
      const int row = wr + i * 16 + lr;
      af[i] = *(const f16x8*)&Xs[row * 32 + ((lg ^ (row & 3)) * 8)];
    }
#pragma unroll
    for (int j = 0; j < 4; ++j)
      bf[j] = *(const f16x8*)&Ws[(wc + j * 16 + lr) * 32 + lg * 8];
#pragma unroll
    for (int i = 0; i < 4; ++i)
#pragma unroll
      for (int j = 0; j < 4; ++j)
        acc[i][j] = MFMA16(af[i], bf[j], acc[i][j]);
  }

#pragma unroll
  for (int i = 0; i < 4; ++i)
#pragma unroll
    for (int j = 0; j < 4; ++j)
#pragma unroll
      for (int r = 0; r < 4; ++r) {
        const int row = m0 + wr + i * 16 + lg * 4 + r;
        const int col = n0 + wc + j * 16 + lr;
        Q[(size_t)row * N + col] = (__fp16)acc[i][j][r];
      }
}

// ---------------------------------------------------------------------------
// Attention: block = 4 waves, 128 Q-rows of one (b,h); grid 2048.
// K_h / V_h^T staged once into LDS (source-side chunk swizzle), dots in regs,
// in-reg softmax, P transposed through reused K-LDS, PV from LDS.
// ---------------------------------------------------------------------------
__global__ __launch_bounds__(256) void attn_k(
    const __fp16* __restrict__ Q,    // [b*4096][1024]
    const __fp16* __restrict__ Kp,   // [b][256][1024]
    const __fp16* __restrict__ Vpt,  // [b][1024][256]
    float* __restrict__ O) {         // [b*4096][1024] f32
  __shared__ __fp16 Ks[256 * 64];    // 32KB: K tiles; reused as P (8KB/wave)
  __shared__ __fp16 Vs[64 * 256];    // 32KB: V^T tiles
  const int t = threadIdx.x;
  const int lane = t & 63, w = t >> 6;
  const int lr = lane & 15, lg = lane >> 4;
  const int bh = blockIdx.x >> 5, rb = blockIdx.x & 31;
  const int b = bh >> 4, h = bh & 15;
  const int m0 = rb * 128 + w * 32;

  const __fp16* Kph = Kp + (size_t)b * 256 * 1024 + h * 64;
  const __fp16* Vph = Vpt + ((size_t)b * 1024 + h * 64) * 256;
  const __fp16* Qh = Q + ((size_t)(b * 4096 + m0)) * 1024 + h * 64;

#pragma unroll
  for (int i = 0; i < 8; ++i) {
    const int kr = (i * 4 + w) * 8 + (lane >> 3);
    gload_lds16(Kph + (size_t)kr * 1024 + (((lane & 7) ^ (kr & 7)) * 8),
                (char*)Ks + (i * 4 + w) * 1024);
  }
#pragma unroll
  for (int i = 0; i < 8; ++i) {
    const int dd = (i * 4 + w) * 2 + (lane >> 5);
    gload_lds16(Vph + (size_t)dd * 256 + (((lane & 31) ^ (dd & 7)) * 8),
                (char*)Vs + (i * 4 + w) * 1024);
  }

  f16x8 aq[2][2];
#pragma unroll
  for (int mi = 0; mi < 2; ++mi)
#pragma unroll
    for (int s = 0; s < 2; ++s)
      aq[mi][s] =
          *(const f16x8*)(Qh + (size_t)(mi * 16 + lr) * 1024 + s * 32 + lg * 8);

  __syncthreads();

  f32x4 dots[2][16];
#pragma unroll
  for (int mi = 0; mi < 2; ++mi)
#pragma unroll
    for (int jt = 0; jt < 16; ++jt) dots[mi][jt] = (f32x4){0.f, 0.f, 0.f, 0.f};
#pragma unroll
  for (int jt = 0; jt < 16; ++jt) {
    const int r = jt * 16 + lr;
    f16x8 k0 = *(const f16x8*)((const char*)Ks + r * 128 + ((lg ^ (r & 7)) * 16));
    f16x8 k1 =
        *(const f16x8*)((const char*)Ks + r * 128 + (((4 + lg) ^ (r & 7)) * 16));
    dots[0][jt] = MFMA16(aq[0][0], k0, dots[0][jt]);
    dots[0][jt] = MFMA16(aq[0][1], k1, dots[0][jt]);
    dots[1][jt] = MFMA16(aq[1][0], k0, dots[1][jt]);
    dots[1][jt] = MFMA16(aq[1][1], k1, dots[1][jt]);
  }

  float mx[2][4], sm[2][4];
#pragma unroll
  for (int mi = 0; mi < 2; ++mi) {
#pragma unroll
    for (int r = 0; r < 4; ++r) mx[mi][r] = -1e30f;
#pragma unroll
    for (int jt = 0; jt < 16; ++jt)
#pragma unroll
      for (int r = 0; r < 4; ++r) mx[mi][r] = fmaxf(mx[mi][r], dots[mi][jt][r]);
#pragma unroll
    for (int msk = 1; msk <= 8; msk <<= 1)
#pragma unroll
      for (int r = 0; r < 4; ++r)
        mx[mi][r] = fmaxf(mx[mi][r], __shfl_xor(mx[mi][r], msk, 64));
#pragma unroll
    for (int r = 0; r < 4; ++r) sm[mi][r] = 0.f;
#pragma unroll
    for (int jt = 0; jt < 16; ++jt)
#pragma unroll
      for (int r = 0; r < 4; ++r) {
        float p = __expf(dots[mi][jt][r] - mx[mi][r]);
        dots[mi][jt][r] = p;
        sm[mi][r] += p;
      }
#pragma unroll
    for (int msk = 1; msk <= 8; msk <<= 1)
#pragma unroll
      for (int r = 0; r < 4; ++r) sm[mi][r] += __shfl_xor(sm[mi][r], msk, 64);
  }

  __syncthreads();  // all waves done reading Ks -> safe to reuse as P

  char* Pw = (char*)Ks + w * 8192;  // 16 rows x 512B
#pragma unroll
  for (int mi = 0; mi < 2; ++mi) {
#pragma unroll
    for (int jt = 0; jt < 16; ++jt)
#pragma unroll
      for (int r = 0; r < 4; ++r) {
        const int m = lg * 4 + r;
        const int ch = (2 * jt + (lr >> 3)) ^ (m & 7);
        *(__fp16*)(Pw + m * 512 + ch * 16 + (lr & 7) * 2) =
            (__fp16)dots[mi][jt][r];
      }

    f32x4 o[4];
#pragma unroll
    for (int j = 0; j < 4; ++j) o[j] = (f32x4){0.f, 0.f, 0.f, 0.f};
#pragma unroll
    for (int ks = 0; ks < 8; ++ks) {
      f16x8 pa =
          *(const f16x8*)(Pw + lr * 512 + (((ks * 4 + lg) ^ (lr & 7)) * 16));
#pragma unroll
      for (int jt2 = 0; jt2 < 4; ++jt2) {
        const int dd = jt2 * 16 + lr;
        f16x8 bv = *(const f16x8*)((const char*)Vs + dd * 512 +
                                   (((ks * 4 + lg) ^ (dd & 7)) * 16));
        o[jt2] = MFMA16(pa, bv, o[jt2]);
      }
    }

#pragma unroll
    for (int jt2 = 0; jt2 < 4; ++jt2)
#pragma unroll
      for (int r = 0; r < 4; ++r) {
        const size_t row = (size_t)(b * 4096 + m0 + mi * 16 + lg * 4 + r);
        O[row * 1024 + h * 64 + jt2 * 16 + lr] = o[jt2][r] / sm[mi][r];
      }
  }
}

// ---------------------------------------------------------------------------
extern "C" void kernel_launch(void* const* d_in, const int* in_sizes, int n_in,
                              void* d_out, int out_size, void* d_ws, size_t ws_size,
                              hipStream_t stream) {
  (void)in_sizes; (void)n_in; (void)out_size; (void)ws_size;
  const float* x  = (const float*)d_in[0];
  const float* Wq = (const float*)d_in[1];
  const float* Wk = (const float*)d_in[2];
  const float* Wv = (const float*)d_in[3];
  const float* pk = (const float*)d_in[4];
  const float* pv = (const float*)d_in[5];
  float* out = (float*)d_out;

  // ws layout (f16 halfwords), total ~52.4 MB.
  // The Qh region (33.5 MB) doubles as the f32 partials buffer (32 MB) for
  // stage1; gemm_q overwrites it later (stream-ordered after stage1_reduce).
  __fp16* Qh  = (__fp16*)d_ws;                       // 16384*1024 f16
  __fp16* WqT = Qh  + (size_t)16384 * 1024;          // 1024*1024 each
  __fp16* WkT = WqT + (size_t)1024 * 1024;
  __fp16* WvT = WkT + (size_t)1024 * 1024;
  __fp16* pkT = WvT + (size_t)1024 * 1024;           // 256*4096 each
  __fp16* pvT = pkT + (size_t)256 * 4096;
  __fp16* Xk  = pvT + (size_t)256 * 4096;            // 4*256*1024 each
  __fp16* Xv  = Xk  + (size_t)4 * 256 * 1024;
  __fp16* Kp  = Xv  + (size_t)4 * 256 * 1024;
  __fp16* Vpt = Kp  + (size_t)4 * 256 * 1024;
  float* Pk = (float*)d_ws;                          // 16*256*1024 f32 each
  float* Pv = Pk + (size_t)16 * 256 * 1024;

  const dim3 bb(256);

  // 0. one-time transposes (f32 -> f16)
  tr_cvt<<<dim3(32, 32), bb, 0, stream>>>(Wq, WqT, 1024, 1024);
  tr_cvt<<<dim3(32, 32), bb, 0, stream>>>(Wk, WkT, 1024, 1024);
  tr_cvt<<<dim3(32, 32), bb, 0, stream>>>(Wv, WvT, 1024, 1024);
  tr_cvt<<<dim3(8, 128), bb, 0, stream>>>(pk, pkT, 4096, 256);
  tr_cvt<<<dim3(8, 128), bb, 0, stream>>>(pv, pvT, 4096, 256);

  // 1. split-K low-rank projections of X + reduce
  stage1_partial<<<dim3(4, 16, 16), bb, 0, stream>>>(pkT, pvT, x, Pk, Pv);
  stage1_reduce<<<dim3(1024), bb, 0, stream>>>(Pk, Pv, Xk, Xv);

  // 2. Kp = Xk . Wk ; VpT = (Xv . Wv)^T
  bt64<<<dim3(4, 16, 4), bb, 0, stream>>>(Xk, 256LL * 1024, WkT, 0LL,
                                          Kp, 1024, 256LL * 1024);
  bt64<<<dim3(16, 4, 4), bb, 0, stream>>>(WvT, 0LL, Xv, 256LL * 1024,
                                          Vpt, 256, 1024LL * 256);

  // 3. Q projection (overwrites partials region - stream-ordered)
  gemm_q<<<dim3(128, 8), bb, 0, stream>>>(x, WqT, Qh);

  // 4. attention (LDS-staged K/V)
  attn_k<<<dim3(2048), bb, 0, stream>>>(Qh, Kp, Vpt, out);
}

// Round 7
// 220.619 us; speedup vs baseline: 2.9909x; 1.0497x over previous
//
#include <hip/hip_runtime.h>

// ---------------------------------------------------------------------------
// Linformer self-attention, fp32 I/O, fp16 MFMA internally, MI355X (gfx950)
// b=4 n=4096 d=1024 h=16 dh=64 k=256  (no 1/sqrt(dh) scale per reference)
//
// Key algebra: proj_k^T (X Wk) == (proj_k^T X) Wk  -> K/V paths cost 4x less.
// LDS discipline (this round): every staged tile uses 64B rows with chunk
// position c ^ ((row>>1)&3); global_load_lds sides pre-swizzle the SOURCE
// chunk ((lane&3)^((lane>>3)&3)) so reads are ~2-way (free) instead of 8-way.
// ---------------------------------------------------------------------------

typedef __fp16 f16x8 __attribute__((ext_vector_type(8)));
typedef __fp16 f16x2 __attribute__((ext_vector_type(2)));
typedef float fl4 __attribute__((ext_vector_type(4)));
typedef float f32x4 __attribute__((ext_vector_type(4)));
typedef unsigned int u32x2 __attribute__((ext_vector_type(2)));

#define MFMA16(a, b, c) __builtin_amdgcn_mfma_f32_16x16x32_f16((a), (b), (c), 0, 0, 0)

__device__ __forceinline__ unsigned int pk2u(float a, float b) {
  f16x2 p = __builtin_amdgcn_cvt_pkrtz(a, b);  // low = a, high = b
  return __builtin_bit_cast(unsigned int, p);
}

__device__ __forceinline__ f16x8 pk8(fl4 a, fl4 b) {
  f16x2 p0 = __builtin_amdgcn_cvt_pkrtz(a[0], a[1]);
  f16x2 p1 = __builtin_amdgcn_cvt_pkrtz(a[2], a[3]);
  f16x2 p2 = __builtin_amdgcn_cvt_pkrtz(b[0], b[1]);
  f16x2 p3 = __builtin_amdgcn_cvt_pkrtz(b[2], b[3]);
  f16x8 r;
  r[0] = p0[0]; r[1] = p0[1]; r[2] = p1[0]; r[3] = p1[1];
  r[4] = p2[0]; r[5] = p2[1]; r[6] = p3[0]; r[7] = p3[1];
  return r;
}

__device__ __forceinline__ void gload_lds16(const __fp16* g, void* lds_base) {
  __builtin_amdgcn_global_load_lds(
      (const __attribute__((address_space(1))) void*)g,
      (__attribute__((address_space(3))) void*)lds_base, 16, 0, 0);
}

// read a swizzled 64B-row tile fragment: logical chunk lg of `row`
__device__ __forceinline__ f16x8 rd_swz(const __fp16* base, int row, int lg) {
  return *(const f16x8*)((const char*)base + row * 64 +
                         ((lg ^ ((row >> 1) & 3)) * 16));
}

// ---------------------------------------------------------------------------
// Transpose + convert: in f32 [R][C] -> out f16 [C][R]. 32x32 tiles.
// ---------------------------------------------------------------------------
__global__ __launch_bounds__(256) void tr_cvt(
    const float* __restrict__ in, __fp16* __restrict__ out, int R, int C) {
  __shared__ float tile[32][33];
  const int t = threadIdx.x;
  const int c0 = blockIdx.x * 32, r0 = blockIdx.y * 32;
  {
    const int r = t >> 3, cg = (t & 7) * 4;
    fl4 v = *(const fl4*)(in + (size_t)(r0 + r) * C + c0 + cg);
    tile[r][cg] = v[0]; tile[r][cg + 1] = v[1];
    tile[r][cg + 2] = v[2]; tile[r][cg + 3] = v[3];
  }
  __syncthreads();
  {
    const int cc = t >> 3, rg = (t & 7) * 4;
    u32x2 p;
    p[0] = pk2u(tile[rg + 0][cc], tile[rg + 1][cc]);
    p[1] = pk2u(tile[rg + 2][cc], tile[rg + 3][cc]);
    *(u32x2*)(out + (size_t)(c0 + cc) * R + r0 + rg) = p;
  }
}

// ---------------------------------------------------------------------------
// Stage 1, split-K partials:
//   Pk[z][kk][dd] = sum_{n in chunk c} pkT[kk][n] * X[b][n][dd]   (z = c*4+b)
// pkT/pvT tiles: gload_lds, source chunk pre-swizzled. X^T tile: coalesced
// paired-row fl4 reads -> pk2u -> u32 writes at pair-pos p^((qd&3)<<2).
// ---------------------------------------------------------------------------
__global__ __launch_bounds__(256) void stage1_partial(
    const __fp16* __restrict__ pkT,  // [256][4096]
    const __fp16* __restrict__ pvT,  // [256][4096]
    const float* __restrict__ X,     // [b][4096][1024]
    float* __restrict__ Pk,          // [16][256][1024]
    float* __restrict__ Pv) {        // [16][256][1024]
  __shared__ __fp16 Ak[64 * 32];
  __shared__ __fp16 Av[64 * 32];
  __shared__ __fp16 Bt[64 * 32];  // [dd][n]
  const int t = threadIdx.x;
  const int lane = t & 63, w = t >> 6;
  const int lr = lane & 15, lg = lane >> 4;
  const int kk0 = blockIdx.x * 64, dd0 = blockIdx.y * 64;
  const int z = blockIdx.z, b = z & 3, c = z >> 2;
  const int wr = (w >> 1) * 32, wc = (w & 1) * 32;

  f32x4 acck[2][2], accv[2][2];
#pragma unroll
  for (int i = 0; i < 2; ++i)
#pragma unroll
    for (int j = 0; j < 2; ++j) {
      acck[i][j] = (f32x4){0.f, 0.f, 0.f, 0.f};
      accv[i][j] = (f32x4){0.f, 0.f, 0.f, 0.f};
    }

  // pkT/pvT gload: wave w -> rows w*16+(lane>>2), source chunk pre-swizzled
  const int gl_row = w * 16 + (lane >> 2);
  const int gl_ch = (lane & 3) ^ ((lane >> 3) & 3);
  const __fp16* pkSrc = pkT + (size_t)(kk0 + gl_row) * 4096 + c * 1024 + gl_ch * 8;
  const __fp16* pvSrc = pvT + (size_t)(kk0 + gl_row) * 4096 + c * 1024 + gl_ch * 8;
  // X staging: n-pair p = t>>4, dd-quad qd = t&15
  const int p = t >> 4, qd = t & 15;
  const int ppos = p ^ ((qd & 3) << 2);
  const float* xSrc =
      X + ((size_t)b * 4096 + c * 1024 + 2 * p) * 1024 + dd0 + qd * 4;

  for (int it = 0; it < 32; ++it) {
    const int n0 = it * 32;
    fl4 x0 = *(const fl4*)(xSrc + (size_t)n0 * 1024);
    fl4 x1 = *(const fl4*)(xSrc + (size_t)n0 * 1024 + 1024);
    __syncthreads();
    gload_lds16(pkSrc + n0, (char*)Ak + w * 1024);
    gload_lds16(pvSrc + n0, (char*)Av + w * 1024);
#pragma unroll
    for (int j = 0; j < 4; ++j)
      *(unsigned int*)((char*)Bt + (qd * 4 + j) * 64 + ppos * 4) =
          pk2u(x0[j], x1[j]);
    __syncthreads();

    f16x8 ak[2], av[2], bx[2];
#pragma unroll
    for (int i = 0; i < 2; ++i) {
      ak[i] = rd_swz(Ak, wr + i * 16 + lr, lg);
      av[i] = rd_swz(Av, wr + i * 16 + lr, lg);
    }
#pragma unroll
    for (int j = 0; j < 2; ++j) {
      const int dd = wc + j * 16 + lr;
      bx[j] = *(const f16x8*)((const char*)Bt + dd * 64 +
                              ((lg ^ ((dd >> 2) & 3)) * 16));
    }
#pragma unroll
    for (int i = 0; i < 2; ++i)
#pragma unroll
      for (int j = 0; j < 2; ++j) {
        acck[i][j] = MFMA16(ak[i], bx[j], acck[i][j]);
        accv[i][j] = MFMA16(av[i], bx[j], accv[i][j]);
      }
  }

#pragma unroll
  for (int i = 0; i < 2; ++i)
#pragma unroll
    for (int j = 0; j < 2; ++j)
#pragma unroll
      for (int r = 0; r < 4; ++r) {
        const size_t row = (size_t)z * 256 + kk0 + wr + i * 16 + lg * 4 + r;
        const int col = dd0 + wc + j * 16 + lr;
        Pk[row * 1024 + col] = acck[i][j][r];
        Pv[row * 1024 + col] = accv[i][j][r];
      }
}

// ---------------------------------------------------------------------------
// Stage 1 reduce: Xk = f16(sum_c Pk[c*4+b]), Xv likewise. 4 f32/thread.
// ---------------------------------------------------------------------------
__global__ __launch_bounds__(256) void stage1_reduce(
    const float* __restrict__ Pk, const float* __restrict__ Pv,
    __fp16* __restrict__ Xk, __fp16* __restrict__ Xv) {
  const size_t base = ((size_t)blockIdx.x * 256 + threadIdx.x) * 4;
  const int b = (int)(base >> 18);          // 256K elems per batch slab
  const size_t rem = base & 0x3FFFFu;
  fl4 ak = (fl4){0.f, 0.f, 0.f, 0.f}, av = (fl4){0.f, 0.f, 0.f, 0.f};
#pragma unroll
  for (int c = 0; c < 4; ++c) {
    const size_t off = (((size_t)(c * 4 + b)) << 18) + rem;
    ak += *(const fl4*)(Pk + off);
    av += *(const fl4*)(Pv + off);
  }
  u32x2 pkp, pvp;
  pkp[0] = pk2u(ak[0], ak[1]); pkp[1] = pk2u(ak[2], ak[3]);
  pvp[0] = pk2u(av[0], av[1]); pvp[1] = pk2u(av[2], av[3]);
  *(u32x2*)(Xk + base) = pkp;
  *(u32x2*)(Xv + base) = pvp;
}

// ---------------------------------------------------------------------------
// Generic small BT-GEMM: C[i][j] (f16) = sum_e A[i][e] * B[j][e], E=1024.
// Both tiles gload_lds with source chunk pre-swizzle; swizzled reads.
// ---------------------------------------------------------------------------
__global__ __launch_bounds__(256) void bt64(
    const __fp16* __restrict__ A, long long bsA,
    const __fp16* __restrict__ B, long long bsB,
    __fp16* __restrict__ C, int ldC, long long bsC) {
  constexpr int E = 1024;
  __shared__ __fp16 As[64 * 32];
  __shared__ __fp16 Bs[64 * 32];
  const int t = threadIdx.x;
  const int lane = t & 63, w = t >> 6;
  const int lr = lane & 15, lg = lane >> 4;
  const int i0 = blockIdx.x * 64, j0 = blockIdx.y * 64;
  A += (size_t)blockIdx.z * (size_t)bsA;
  B += (size_t)blockIdx.z * (size_t)bsB;
  C += (size_t)blockIdx.z * (size_t)bsC;
  const int wr = (w >> 1) * 32, wc = (w & 1) * 32;

  f32x4 acc[2][2];
#pragma unroll
  for (int i = 0; i < 2; ++i)
#pragma unroll
    for (int j = 0; j < 2; ++j) acc[i][j] = (f32x4){0.f, 0.f, 0.f, 0.f};

  const int gl_row = w * 16 + (lane >> 2);
  const int gl_ch = (lane & 3) ^ ((lane >> 3) & 3);
  const __fp16* aSrc = A + (size_t)(i0 + gl_row) * E + gl_ch * 8;
  const __fp16* bSrc = B + (size_t)(j0 + gl_row) * E + gl_ch * 8;

  for (int e0 = 0; e0 < E; e0 += 32) {
    __syncthreads();
    gload_lds16(aSrc + e0, (char*)As + w * 1024);
    gload_lds16(bSrc + e0, (char*)Bs + w * 1024);
    __syncthreads();

    f16x8 af[2], bf[2];
#pragma unroll
    for (int i = 0; i < 2; ++i)
      af[i] = rd_swz(As, wr + i * 16 + lr, lg);
#pragma unroll
    for (int j = 0; j < 2; ++j)
      bf[j] = rd_swz(Bs, wc + j * 16 + lr, lg);
#pragma unroll
    for (int i = 0; i < 2; ++i)
#pragma unroll
      for (int j = 0; j < 2; ++j)
        acc[i][j] = MFMA16(af[i], bf[j], acc[i][j]);
  }

#pragma unroll
  for (int i = 0; i < 2; ++i)
#pragma unroll
    for (int j = 0; j < 2; ++j)
#pragma unroll
      for (int r = 0; r < 4; ++r) {
        const int row = i0 + wr + i * 16 + lg * 4 + r;
        const int col = j0 + wc + j * 16 + lr;
        C[(size_t)row * ldC + col] = (__fp16)acc[i][j][r];
      }
}

// ---------------------------------------------------------------------------
// Q-path GEMM: Qh[16384][1024] (f16) = X(f32) . WqT^T, 128x128 tile, BK=32.
// X: coalesced fl4 reads (4 lanes x 64B per row), pk8 -> swizzled b128 write.
// WqT: gload_lds, source chunk pre-swizzled. Reads: rd_swz (2-way, free).
// ---------------------------------------------------------------------------
__global__ __launch_bounds__(256) void gemm_q(
    const float* __restrict__ X,
    const __fp16* __restrict__ WT,   // [1024][1024], WT[n][k] = W[k][n]
    __fp16* __restrict__ Q) {
  constexpr int K = 1024, N = 1024;
  __shared__ __fp16 Xs[128 * 32];
  __shared__ __fp16 Ws[128 * 32];
  const int t = threadIdx.x;
  const int lane = t & 63, w = t >> 6;
  const int lr = lane & 15, lg = lane >> 4;
  const int m0 = blockIdx.x * 128, n0 = blockIdx.y * 128;
  const int wr = (w >> 1) * 64, wc = (w & 1) * 64;

  f32x4 acc[4][4];
#pragma unroll
  for (int i = 0; i < 4; ++i)
#pragma unroll
    for (int j = 0; j < 4; ++j) acc[i][j] = (f32x4){0.f, 0.f, 0.f, 0.f};

  // X staging: row = t>>2 (+64 for pass 2), chunk (t&3), pos swizzled
  const int xrow = t >> 2;
  const int xpos = (t & 3) ^ ((t >> 3) & 3);
  const float* xSrc1 = X + (size_t)(m0 + xrow) * K + (t & 3) * 8;
  const float* xSrc2 = xSrc1 + (size_t)64 * K;
  // W staging: wave w -> rows w*16+(lane>>2) and +64, source chunk swizzled
  const int gl_row = w * 16 + (lane >> 2);
  const int gl_ch = (lane & 3) ^ ((lane >> 3) & 3);
  const __fp16* wSrc0 = WT + (size_t)(n0 + gl_row) * K + gl_ch * 8;
  const __fp16* wSrc1 = WT + (size_t)(n0 + 64 + gl_row) * K + gl_ch * 8;

  for (int k0 = 0; k0 < K; k0 += 32) {
    fl4 a0 = *(const fl4*)(xSrc1 + k0);
    fl4 a1 = *(const fl4*)(xSrc1 + k0 + 4);
    fl4 a2 = *(const fl4*)(xSrc2 + k0);
    fl4 a3 = *(const fl4*)(xSrc2 + k0 + 4);
    __syncthreads();
    gload_lds16(wSrc0 + k0, (char*)Ws + w * 1024);
    gload_lds16(wSrc1 + k0, (char*)Ws + 4096 + w * 1024);
    *(f16x8*)((char*)Xs + xrow * 64 + xpos * 16) = pk8(a0, a1);
    *(f16x8*)((char*)Xs + (64 + xrow) * 64 + xpos * 16) = pk8(a2, a3);
    __syncthreads();

    f16x8 af[4], bf[4];
#pragma unroll
    for (int i = 0; i < 4; ++i)
      af[i] = rd_swz(Xs, wr + i * 16 + lr, lg);
#pragma unroll
    for (int j = 0; j < 4; ++j)
      bf[j] = rd_swz(Ws, wc + j * 16 + lr, lg);
#pragma unroll
    for (int i = 0; i < 4; ++i)
#pragma unroll
      for (int j = 0; j < 4; ++j)
        acc[i][j] = MFMA16(af[i], bf[j], acc[i][j]);
  }

#pragma unroll
  for (int i = 0; i < 4; ++i)
#pragma unroll
    for (int j = 0; j < 4; ++j)
#pragma unroll
      for (int r = 0; r < 4; ++r) {
        const int row = m0 + wr + i * 16 + lg * 4 + r;
        const int col = n0 + wc + j * 16 + lr;
        Q[(size_t)row * N + col] = (__fp16)acc[i][j][r];
      }
}

// ---------------------------------------------------------------------------
// Attention: block = 4 waves, 128 Q-rows of one (b,h); grid 2048. (unchanged)
// ---------------------------------------------------------------------------
__global__ __launch_bounds__(256) void attn_k(
    const __fp16* __restrict__ Q,    // [b*4096][1024]
    const __fp16* __restrict__ Kp,   // [b][256][1024]
    const __fp16* __restrict__ Vpt,  // [b][1024][256]
    float* __restrict__ O) {         // [b*4096][1024] f32
  __shared__ __fp16 Ks[256 * 64];    // 32KB: K tiles; reused as P (8KB/wave)
  __shared__ __fp16 Vs[64 * 256];    // 32KB: V^T tiles
  const int t = threadIdx.x;
  const int lane = t & 63, w = t >> 6;
  const int lr = lane & 15, lg = lane >> 4;
  const int bh = blockIdx.x >> 5, rb = blockIdx.x & 31;
  const int b = bh >> 4, h = bh & 15;
  const int m0 = rb * 128 + w * 32;

  const __fp16* Kph = Kp + (size_t)b * 256 * 1024 + h * 64;
  const __fp16* Vph = Vpt + ((size_t)b * 1024 + h * 64) * 256;
  const __fp16* Qh = Q + ((size_t)(b * 4096 + m0)) * 1024 + h * 64;

#pragma unroll
  for (int i = 0; i < 8; ++i) {
    const int kr = (i * 4 + w) * 8 + (lane >> 3);
    gload_lds16(Kph + (size_t)kr * 1024 + (((lane & 7) ^ (kr & 7)) * 8),
                (char*)Ks + (i * 4 + w) * 1024);
  }
#pragma unroll
  for (int i = 0; i < 8; ++i) {
    const int dd = (i * 4 + w) * 2 + (lane >> 5);
    gload_lds16(Vph + (size_t)dd * 256 + (((lane & 31) ^ (dd & 7)) * 8),
                (char*)Vs + (i * 4 + w) * 1024);
  }

  f16x8 aq[2][2];
#pragma unroll
  for (int mi = 0; mi < 2; ++mi)
#pragma unroll
    for (int s = 0; s < 2; ++s)
      aq[mi][s] =
          *(const f16x8*)(Qh + (size_t)(mi * 16 + lr) * 1024 + s * 32 + lg * 8);

  __syncthreads();

  f32x4 dots[2][16];
#pragma unroll
  for (int mi = 0; mi < 2; ++mi)
#pragma unroll
    for (int jt = 0; jt < 16; ++jt) dots[mi][jt] = (f32x4){0.f, 0.f, 0.f, 0.f};
#pragma unroll
  for (int jt = 0; jt < 16; ++jt) {
    const int r = jt * 16 + lr;
    f16x8 k0 = *(const f16x8*)((const char*)Ks + r * 128 + ((lg ^ (r & 7)) * 16));
    f16x8 k1 =
        *(const f16x8*)((const char*)Ks + r * 128 + (((4 + lg) ^ (r & 7)) * 16));
    dots[0][jt] = MFMA16(aq[0][0], k0, dots[0][jt]);
    dots[0][jt] = MFMA16(aq[0][1], k1, dots[0][jt]);
    dots[1][jt] = MFMA16(aq[1][0], k0, dots[1][jt]);
    dots[1][jt] = MFMA16(aq[1][1], k1, dots[1][jt]);
  }

  float mx[2][4], sm[2][4];
#pragma unroll
  for (int mi = 0; mi < 2; ++mi) {
#pragma unroll
    for (int r = 0; r < 4; ++r) mx[mi][r] = -1e30f;
#pragma unroll
    for (int jt = 0; jt < 16; ++jt)
#pragma unroll
      for (int r = 0; r < 4; ++r) mx[mi][r] = fmaxf(mx[mi][r], dots[mi][jt][r]);
#pragma unroll
    for (int msk = 1; msk <= 8; msk <<= 1)
#pragma unroll
      for (int r = 0; r < 4; ++r)
        mx[mi][r] = fmaxf(mx[mi][r], __shfl_xor(mx[mi][r], msk, 64));
#pragma unroll
    for (int r = 0; r < 4; ++r) sm[mi][r] = 0.f;
#pragma unroll
    for (int jt = 0; jt < 16; ++jt)
#pragma unroll
      for (int r = 0; r < 4; ++r) {
        float p = __expf(dots[mi][jt][r] - mx[mi][r]);
        dots[mi][jt][r] = p;
        sm[mi][r] += p;
      }
#pragma unroll
    for (int msk = 1; msk <= 8; msk <<= 1)
#pragma unroll
      for (int r = 0; r < 4; ++r) sm[mi][r] += __shfl_xor(sm[mi][r], msk, 64);
  }

  __syncthreads();  // all waves done reading Ks -> safe to reuse as P

  char* Pw = (char*)Ks + w * 8192;  // 16 rows x 512B
#pragma unroll
  for (int mi = 0; mi < 2; ++mi) {
#pragma unroll
    for (int jt = 0; jt < 16; ++jt)
#pragma unroll
      for (int r = 0; r < 4; ++r) {
        const int m = lg * 4 + r;
        const int ch = (2 * jt + (lr >> 3)) ^ (m & 7);
        *(__fp16*)(Pw + m * 512 + ch * 16 + (lr & 7) * 2) =
            (__fp16)dots[mi][jt][r];
      }

    f32x4 o[4];
#pragma unroll
    for (int j = 0; j < 4; ++j) o[j] = (f32x4){0.f, 0.f, 0.f, 0.f};
#pragma unroll
    for (int ks = 0; ks < 8; ++ks) {
      f16x8 pa =
          *(const f16x8*)(Pw + lr * 512 + (((ks * 4 + lg) ^ (lr & 7)) * 16));
#pragma unroll
      for (int jt2 = 0; jt2 < 4; ++jt2) {
        const int dd = jt2 * 16 + lr;
        f16x8 bv = *(const f16x8*)((const char*)Vs + dd * 512 +
                                   (((ks * 4 + lg) ^ (dd & 7)) * 16));
        o[jt2] = MFMA16(pa, bv, o[jt2]);
      }
    }

#pragma unroll
    for (int jt2 = 0; jt2 < 4; ++jt2)
#pragma unroll
      for (int r = 0; r < 4; ++r) {
        const size_t row = (size_t)(b * 4096 + m0 + mi * 16 + lg * 4 + r);
        O[row * 1024 + h * 64 + jt2 * 16 + lr] = o[jt2][r] / sm[mi][r];
      }
  }
}

// ---------------------------------------------------------------------------
extern "C" void kernel_launch(void* const* d_in, const int* in_sizes, int n_in,
                              void* d_out, int out_size, void* d_ws, size_t ws_size,
                              hipStream_t stream) {
  (void)in_sizes; (void)n_in; (void)out_size; (void)ws_size;
  const float* x  = (const float*)d_in[0];
  const float* Wq = (const float*)d_in[1];
  const float* Wk = (const float*)d_in[2];
  const float* Wv = (const float*)d_in[3];
  const float* pk = (const float*)d_in[4];
  const float* pv = (const float*)d_in[5];
  float* out = (float*)d_out;

  // ws layout (f16 halfwords), total ~52.4 MB.
  // The Qh region (33.5 MB) doubles as the f32 partials buffer (32 MB) for
  // stage1; gemm_q overwrites it later (stream-ordered after stage1_reduce).
  __fp16* Qh  = (__fp16*)d_ws;                       // 16384*1024 f16
  __fp16* WqT = Qh  + (size_t)16384 * 1024;          // 1024*1024 each
  __fp16* WkT = WqT + (size_t)1024 * 1024;
  __fp16* WvT = WkT + (size_t)1024 * 1024;
  __fp16* pkT = WvT + (size_t)1024 * 1024;           // 256*4096 each
  __fp16* pvT = pkT + (size_t)256 * 4096;
  __fp16* Xk  = pvT + (size_t)256 * 4096;            // 4*256*1024 each
  __fp16* Xv  = Xk  + (size_t)4 * 256 * 1024;
  __fp16* Kp  = Xv  + (size_t)4 * 256 * 1024;
  __fp16* Vpt = Kp  + (size_t)4 * 256 * 1024;
  float* Pk = (float*)d_ws;                          // 16*256*1024 f32 each
  float* Pv = Pk + (size_t)16 * 256 * 1024;

  const dim3 bb(256);

  // 0. one-time transposes (f32 -> f16)
  tr_cvt<<<dim3(32, 32), bb, 0, stream>>>(Wq, WqT, 1024, 1024);
  tr_cvt<<<dim3(32, 32), bb, 0, stream>>>(Wk, WkT, 1024, 1024);
  tr_cvt<<<dim3(32, 32), bb, 0, stream>>>(Wv, WvT, 1024, 1024);
  tr_cvt<<<dim3(8, 128), bb, 0, stream>>>(pk, pkT, 4096, 256);
  tr_cvt<<<dim3(8, 128), bb, 0, stream>>>(pv, pvT, 4096, 256);

  // 1. split-K low-rank projections of X + reduce
  stage1_partial<<<dim3(4, 16, 16), bb, 0, stream>>>(pkT, pvT, x, Pk, Pv);
  stage1_reduce<<<dim3(1024), bb, 0, stream>>>(Pk, Pv, Xk, Xv);

  // 2. Kp = Xk . Wk ; VpT = (Xv . Wv)^T
  bt64<<<dim3(4, 16, 4), bb, 0, stream>>>(Xk, 256LL * 1024, WkT, 0LL,
                                          Kp, 1024, 256LL * 1024);
  bt64<<<dim3(16, 4, 4), bb, 0, stream>>>(WvT, 0LL, Xv, 256LL * 1024,
                                          Vpt, 256, 1024LL * 256);

  // 3. Q projection (overwrites partials region - stream-ordered)
  gemm_q<<<dim3(128, 8), bb, 0, stream>>>(x, WqT, Qh);

  // 4. attention (LDS-staged K/V)
  attn_k<<<dim3(2048), bb, 0, stream>>>(Qh, Kp, Vpt, out);
}

// Round 8
// 198.339 us; speedup vs baseline: 3.3269x; 1.1123x over previous
//
#include <hip/hip_runtime.h>

// ---------------------------------------------------------------------------
// Linformer self-attention, fp32 I/O, fp16 MFMA internally, MI355X (gfx950)
// b=4 n=4096 d=1024 h=16 dh=64 k=256  (no 1/sqrt(dh) scale per reference)
//
// Key algebra: proj_k^T (X Wk) == (proj_k^T X) Wk  -> K/V paths cost 4x less.
// attn v3: 32KB LDS (K then V), swapped QK^T (lane-local P rows), in-register
// P->A-frag via cvt_pk + ds_bpermute (no P LDS, no extra barrier).
// ---------------------------------------------------------------------------

typedef __fp16 f16x8 __attribute__((ext_vector_type(8)));
typedef __fp16 f16x2 __attribute__((ext_vector_type(2)));
typedef float fl4 __attribute__((ext_vector_type(4)));
typedef float f32x4 __attribute__((ext_vector_type(4)));
typedef unsigned int u32x2 __attribute__((ext_vector_type(2)));
typedef unsigned int u32x4 __attribute__((ext_vector_type(4)));

#define MFMA16(a, b, c) __builtin_amdgcn_mfma_f32_16x16x32_f16((a), (b), (c), 0, 0, 0)

__device__ __forceinline__ unsigned int pk2u(float a, float b) {
  f16x2 p = __builtin_amdgcn_cvt_pkrtz(a, b);  // low = a, high = b
  return __builtin_bit_cast(unsigned int, p);
}

__device__ __forceinline__ f16x8 pk8(fl4 a, fl4 b) {
  f16x2 p0 = __builtin_amdgcn_cvt_pkrtz(a[0], a[1]);
  f16x2 p1 = __builtin_amdgcn_cvt_pkrtz(a[2], a[3]);
  f16x2 p2 = __builtin_amdgcn_cvt_pkrtz(b[0], b[1]);
  f16x2 p3 = __builtin_amdgcn_cvt_pkrtz(b[2], b[3]);
  f16x8 r;
  r[0] = p0[0]; r[1] = p0[1]; r[2] = p1[0]; r[3] = p1[1];
  r[4] = p2[0]; r[5] = p2[1]; r[6] = p3[0]; r[7] = p3[1];
  return r;
}

__device__ __forceinline__ void gload_lds16(const __fp16* g, void* lds_base) {
  __builtin_amdgcn_global_load_lds(
      (const __attribute__((address_space(1))) void*)g,
      (__attribute__((address_space(3))) void*)lds_base, 16, 0, 0);
}

// read a swizzled 64B-row tile fragment: logical chunk lg of `row`
__device__ __forceinline__ f16x8 rd_swz(const __fp16* base, int row, int lg) {
  return *(const f16x8*)((const char*)base + row * 64 +
                         ((lg ^ ((row >> 1) & 3)) * 16));
}

// ---------------------------------------------------------------------------
// Transpose + convert: in f32 [R][C] -> out f16 [C][R]. 32x32 tiles.
// ---------------------------------------------------------------------------
__global__ __launch_bounds__(256) void tr_cvt(
    const float* __restrict__ in, __fp16* __restrict__ out, int R, int C) {
  __shared__ float tile[32][33];
  const int t = threadIdx.x;
  const int c0 = blockIdx.x * 32, r0 = blockIdx.y * 32;
  {
    const int r = t >> 3, cg = (t & 7) * 4;
    fl4 v = *(const fl4*)(in + (size_t)(r0 + r) * C + c0 + cg);
    tile[r][cg] = v[0]; tile[r][cg + 1] = v[1];
    tile[r][cg + 2] = v[2]; tile[r][cg + 3] = v[3];
  }
  __syncthreads();
  {
    const int cc = t >> 3, rg = (t & 7) * 4;
    u32x2 p;
    p[0] = pk2u(tile[rg + 0][cc], tile[rg + 1][cc]);
    p[1] = pk2u(tile[rg + 2][cc], tile[rg + 3][cc]);
    *(u32x2*)(out + (size_t)(c0 + cc) * R + r0 + rg) = p;
  }
}

// ---------------------------------------------------------------------------
// Stage 1, split-K partials:
//   Pk[z][kk][dd] = sum_{n in chunk c} pkT[kk][n] * X[b][n][dd]   (z = c*4+b)
// ---------------------------------------------------------------------------
__global__ __launch_bounds__(256) void stage1_partial(
    const __fp16* __restrict__ pkT,  // [256][4096]
    const __fp16* __restrict__ pvT,  // [256][4096]
    const float* __restrict__ X,     // [b][4096][1024]
    float* __restrict__ Pk,          // [16][256][1024]
    float* __restrict__ Pv) {        // [16][256][1024]
  __shared__ __fp16 Ak[64 * 32];
  __shared__ __fp16 Av[64 * 32];
  __shared__ __fp16 Bt[64 * 32];  // [dd][n]
  const int t = threadIdx.x;
  const int lane = t & 63, w = t >> 6;
  const int lr = lane & 15, lg = lane >> 4;
  const int kk0 = blockIdx.x * 64, dd0 = blockIdx.y * 64;
  const int z = blockIdx.z, b = z & 3, c = z >> 2;
  const int wr = (w >> 1) * 32, wc = (w & 1) * 32;

  f32x4 acck[2][2], accv[2][2];
#pragma unroll
  for (int i = 0; i < 2; ++i)
#pragma unroll
    for (int j = 0; j < 2; ++j) {
      acck[i][j] = (f32x4){0.f, 0.f, 0.f, 0.f};
      accv[i][j] = (f32x4){0.f, 0.f, 0.f, 0.f};
    }

  const int gl_row = w * 16 + (lane >> 2);
  const int gl_ch = (lane & 3) ^ ((lane >> 3) & 3);
  const __fp16* pkSrc = pkT + (size_t)(kk0 + gl_row) * 4096 + c * 1024 + gl_ch * 8;
  const __fp16* pvSrc = pvT + (size_t)(kk0 + gl_row) * 4096 + c * 1024 + gl_ch * 8;
  const int p = t >> 4, qd = t & 15;
  const int ppos = p ^ ((qd & 3) << 2);
  const float* xSrc =
      X + ((size_t)b * 4096 + c * 1024 + 2 * p) * 1024 + dd0 + qd * 4;

  for (int it = 0; it < 32; ++it) {
    const int n0 = it * 32;
    fl4 x0 = *(const fl4*)(xSrc + (size_t)n0 * 1024);
    fl4 x1 = *(const fl4*)(xSrc + (size_t)n0 * 1024 + 1024);
    __syncthreads();
    gload_lds16(pkSrc + n0, (char*)Ak + w * 1024);
    gload_lds16(pvSrc + n0, (char*)Av + w * 1024);
#pragma unroll
    for (int j = 0; j < 4; ++j)
      *(unsigned int*)((char*)Bt + (qd * 4 + j) * 64 + ppos * 4) =
          pk2u(x0[j], x1[j]);
    __syncthreads();

    f16x8 ak[2], av[2], bx[2];
#pragma unroll
    for (int i = 0; i < 2; ++i) {
      ak[i] = rd_swz(Ak, wr + i * 16 + lr, lg);
      av[i] = rd_swz(Av, wr + i * 16 + lr, lg);
    }
#pragma unroll
    for (int j = 0; j < 2; ++j) {
      const int dd = wc + j * 16 + lr;
      bx[j] = *(const f16x8*)((const char*)Bt + dd * 64 +
                              ((lg ^ ((dd >> 2) & 3)) * 16));
    }
#pragma unroll
    for (int i = 0; i < 2; ++i)
#pragma unroll
      for (int j = 0; j < 2; ++j) {
        acck[i][j] = MFMA16(ak[i], bx[j], acck[i][j]);
        accv[i][j] = MFMA16(av[i], bx[j], accv[i][j]);
      }
  }

#pragma unroll
  for (int i = 0; i < 2; ++i)
#pragma unroll
    for (int j = 0; j < 2; ++j)
#pragma unroll
      for (int r = 0; r < 4; ++r) {
        const size_t row = (size_t)z * 256 + kk0 + wr + i * 16 + lg * 4 + r;
        const int col = dd0 + wc + j * 16 + lr;
        Pk[row * 1024 + col] = acck[i][j][r];
        Pv[row * 1024 + col] = accv[i][j][r];
      }
}

// ---------------------------------------------------------------------------
// Stage 1 reduce: Xk = f16(sum_c Pk[c*4+b]), Xv likewise. 4 f32/thread.
// ---------------------------------------------------------------------------
__global__ __launch_bounds__(256) void stage1_reduce(
    const float* __restrict__ Pk, const float* __restrict__ Pv,
    __fp16* __restrict__ Xk, __fp16* __restrict__ Xv) {
  const size_t base = ((size_t)blockIdx.x * 256 + threadIdx.x) * 4;
  const int b = (int)(base >> 18);          // 256K elems per batch slab
  const size_t rem = base & 0x3FFFFu;
  fl4 ak = (fl4){0.f, 0.f, 0.f, 0.f}, av = (fl4){0.f, 0.f, 0.f, 0.f};
#pragma unroll
  for (int c = 0; c < 4; ++c) {
    const size_t off = (((size_t)(c * 4 + b)) << 18) + rem;
    ak += *(const fl4*)(Pk + off);
    av += *(const fl4*)(Pv + off);
  }
  u32x2 pkp, pvp;
  pkp[0] = pk2u(ak[0], ak[1]); pkp[1] = pk2u(ak[2], ak[3]);
  pvp[0] = pk2u(av[0], av[1]); pvp[1] = pk2u(av[2], av[3]);
  *(u32x2*)(Xk + base) = pkp;
  *(u32x2*)(Xv + base) = pvp;
}

// ---------------------------------------------------------------------------
// Generic small BT-GEMM: C[i][j] (f16) = sum_e A[i][e] * B[j][e], E=1024.
// ---------------------------------------------------------------------------
__global__ __launch_bounds__(256) void bt64(
    const __fp16* __restrict__ A, long long bsA,
    const __fp16* __restrict__ B, long long bsB,
    __fp16* __restrict__ C, int ldC, long long bsC) {
  constexpr int E = 1024;
  __shared__ __fp16 As[64 * 32];
  __shared__ __fp16 Bs[64 * 32];
  const int t = threadIdx.x;
  const int lane = t & 63, w = t >> 6;
  const int lr = lane & 15, lg = lane >> 4;
  const int i0 = blockIdx.x * 64, j0 = blockIdx.y * 64;
  A += (size_t)blockIdx.z * (size_t)bsA;
  B += (size_t)blockIdx.z * (size_t)bsB;
  C += (size_t)blockIdx.z * (size_t)bsC;
  const int wr = (w >> 1) * 32, wc = (w & 1) * 32;

  f32x4 acc[2][2];
#pragma unroll
  for (int i = 0; i < 2; ++i)
#pragma unroll
    for (int j = 0; j < 2; ++j) acc[i][j] = (f32x4){0.f, 0.f, 0.f, 0.f};

  const int gl_row = w * 16 + (lane >> 2);
  const int gl_ch = (lane & 3) ^ ((lane >> 3) & 3);
  const __fp16* aSrc = A + (size_t)(i0 + gl_row) * E + gl_ch * 8;
  const __fp16* bSrc = B + (size_t)(j0 + gl_row) * E + gl_ch * 8;

  for (int e0 = 0; e0 < E; e0 += 32) {
    __syncthreads();
    gload_lds16(aSrc + e0, (char*)As + w * 1024);
    gload_lds16(bSrc + e0, (char*)Bs + w * 1024);
    __syncthreads();

    f16x8 af[2], bf[2];
#pragma unroll
    for (int i = 0; i < 2; ++i)
      af[i] = rd_swz(As, wr + i * 16 + lr, lg);
#pragma unroll
    for (int j = 0; j < 2; ++j)
      bf[j] = rd_swz(Bs, wc + j * 16 + lr, lg);
#pragma unroll
    for (int i = 0; i < 2; ++i)
#pragma unroll
      for (int j = 0; j < 2; ++j)
        acc[i][j] = MFMA16(af[i], bf[j], acc[i][j]);
  }

#pragma unroll
  for (int i = 0; i < 2; ++i)
#pragma unroll
    for (int j = 0; j < 2; ++j)
#pragma unroll
      for (int r = 0; r < 4; ++r) {
        const int row = i0 + wr + i * 16 + lg * 4 + r;
        const int col = j0 + wc + j * 16 + lr;
        C[(size_t)row * ldC + col] = (__fp16)acc[i][j][r];
      }
}

// ---------------------------------------------------------------------------
// Q-path GEMM: Qh[16384][1024] (f16) = X(f32) . WqT^T, 128x128 tile, BK=32.
// ---------------------------------------------------------------------------
__global__ __launch_bounds__(256) void gemm_q(
    const float* __restrict__ X,
    const __fp16* __restrict__ WT,   // [1024][1024], WT[n][k] = W[k][n]
    __fp16* __restrict__ Q) {
  constexpr int K = 1024, N = 1024;
  __shared__ __fp16 Xs[128 * 32];
  __shared__ __fp16 Ws[128 * 32];
  const int t = threadIdx.x;
  const int lane = t & 63, w = t >> 6;
  const int lr = lane & 15, lg = lane >> 4;
  const int m0 = blockIdx.x * 128, n0 = blockIdx.y * 128;
  const int wr = (w >> 1) * 64, wc = (w & 1) * 64;

  f32x4 acc[4][4];
#pragma unroll
  for (int i = 0; i < 4; ++i)
#pragma unroll
    for (int j = 0; j < 4; ++j) acc[i][j] = (f32x4){0.f, 0.f, 0.f, 0.f};

  const int xrow = t >> 2;
  const int xpos = (t & 3) ^ ((t >> 3) & 3);
  const float* xSrc1 = X + (size_t)(m0 + xrow) * K + (t & 3) * 8;
  const float* xSrc2 = xSrc1 + (size_t)64 * K;
  const int gl_row = w * 16 + (lane >> 2);
  const int gl_ch = (lane & 3) ^ ((lane >> 3) & 3);
  const __fp16* wSrc0 = WT + (size_t)(n0 + gl_row) * K + gl_ch * 8;
  const __fp16* wSrc1 = WT + (size_t)(n0 + 64 + gl_row) * K + gl_ch * 8;

  for (int k0 = 0; k0 < K; k0 += 32) {
    fl4 a0 = *(const fl4*)(xSrc1 + k0);
    fl4 a1 = *(const fl4*)(xSrc1 + k0 + 4);
    fl4 a2 = *(const fl4*)(xSrc2 + k0);
    fl4 a3 = *(const fl4*)(xSrc2 + k0 + 4);
    __syncthreads();
    gload_lds16(wSrc0 + k0, (char*)Ws + w * 1024);
    gload_lds16(wSrc1 + k0, (char*)Ws + 4096 + w * 1024);
    *(f16x8*)((char*)Xs + xrow * 64 + xpos * 16) = pk8(a0, a1);
    *(f16x8*)((char*)Xs + (64 + xrow) * 64 + xpos * 16) = pk8(a2, a3);
    __syncthreads();

    f16x8 af[4], bf[4];
#pragma unroll
    for (int i = 0; i < 4; ++i)
      af[i] = rd_swz(Xs, wr + i * 16 + lr, lg);
#pragma unroll
    for (int j = 0; j < 4; ++j)
      bf[j] = rd_swz(Ws, wc + j * 16 + lr, lg);
#pragma unroll
    for (int i = 0; i < 4; ++i)
#pragma unroll
      for (int j = 0; j < 4; ++j)
        acc[i][j] = MFMA16(af[i], bf[j], acc[i][j]);
  }

#pragma unroll
  for (int i = 0; i < 4; ++i)
#pragma unroll
    for (int j = 0; j < 4; ++j)
#pragma unroll
      for (int r = 0; r < 4; ++r) {
        const int row = m0 + wr + i * 16 + lg * 4 + r;
        const int col = n0 + wc + j * 16 + lr;
        Q[(size_t)row * N + col] = (__fp16)acc[i][j][r];
      }
}

// ---------------------------------------------------------------------------
// Attention v3: block = 4 waves, 128 Q-rows of one (b,h); grid 2048.
// 32KB LDS: K staged (256x64, swizzled) -> swapped QK^T (dots2[kk][q], q=lr
// lane-local rows) -> in-lane softmax (max kept; 2 shfl_xor) -> barrier ->
// V^T staged into same LDS -> PV with P assembled in-register via
// cvt_pk + ds_bpermute (word m from lane group (lg&1)*2+(m>>1),
// jt = ks*2+(lg>>1), selected by lg>>1). No P LDS, 3 barriers total.
// ---------------------------------------------------------------------------
__global__ __launch_bounds__(256) void attn_k(
    const __fp16* __restrict__ Q,    // [b*4096][1024]
    const __fp16* __restrict__ Kp,   // [b][256][1024]
    const __fp16* __restrict__ Vpt,  // [b][1024][256]
    float* __restrict__ O) {         // [b*4096][1024] f32
  __shared__ __fp16 KV[256 * 64];    // 32KB: K tile, then V^T tile
  const int t = threadIdx.x;
  const int lane = t & 63, w = t >> 6;
  const int lr = lane & 15, lg = lane >> 4;
  const int bh = blockIdx.x >> 5, rb = blockIdx.x & 31;
  const int b = bh >> 4, h = bh & 15;
  const int m0 = rb * 128 + w * 32;

  const __fp16* Kph = Kp + (size_t)b * 256 * 1024 + h * 64;
  const __fp16* Vph = Vpt + ((size_t)b * 1024 + h * 64) * 256;
  const __fp16* Qh = Q + ((size_t)(b * 4096 + m0)) * 1024 + h * 64;

  // ---- stage K: rows kk (128B each), source chunk pre-swizzled by kk&7
#pragma unroll
  for (int i = 0; i < 8; ++i) {
    const int kr = (i * 4 + w) * 8 + (lane >> 3);
    gload_lds16(Kph + (size_t)kr * 1024 + (((lane & 7) ^ (kr & 7)) * 8),
                (char*)KV + (i * 4 + w) * 1024);
  }

  // Q B-fragments (col = q row, k = dd), same addressing as A-frag
  f16x8 aq[2][2];
#pragma unroll
  for (int mi = 0; mi < 2; ++mi)
#pragma unroll
    for (int s = 0; s < 2; ++s)
      aq[mi][s] =
          *(const f16x8*)(Qh + (size_t)(mi * 16 + lr) * 1024 + s * 32 + lg * 8);

  __syncthreads();  // K staged

  // ---- swapped QK^T: dots[mi][jt] = S^T[kk = jt*16 + lg*4 + r][q = lr]
  f32x4 dots[2][16];
#pragma unroll
  for (int mi = 0; mi < 2; ++mi)
#pragma unroll
    for (int jt = 0; jt < 16; ++jt) dots[mi][jt] = (f32x4){0.f, 0.f, 0.f, 0.f};
#pragma unroll
  for (int jt = 0; jt < 16; ++jt) {
    const int r = jt * 16 + lr;
    f16x8 k0 = *(const f16x8*)((const char*)KV + r * 128 + ((lg ^ (r & 7)) * 16));
    f16x8 k1 =
        *(const f16x8*)((const char*)KV + r * 128 + (((4 + lg) ^ (r & 7)) * 16));
    dots[0][jt] = MFMA16(k0, aq[0][0], dots[0][jt]);
    dots[0][jt] = MFMA16(k1, aq[0][1], dots[0][jt]);
    dots[1][jt] = MFMA16(k0, aq[1][0], dots[1][jt]);
    dots[1][jt] = MFMA16(k1, aq[1][1], dots[1][jt]);
  }

  // ---- softmax per mi: all 64 lane values belong to row q=lr
  unsigned cpk[2][16][2];
  float smv[2];
#pragma unroll
  for (int mi = 0; mi < 2; ++mi) {
    float mx = -1e30f;
#pragma unroll
    for (int jt = 0; jt < 16; ++jt)
#pragma unroll
      for (int r = 0; r < 4; ++r) mx = fmaxf(mx, dots[mi][jt][r]);
    mx = fmaxf(mx, __shfl_xor(mx, 16, 64));
    mx = fmaxf(mx, __shfl_xor(mx, 32, 64));
    float sm = 0.f;
#pragma unroll
    for (int jt = 0; jt < 16; ++jt) {
#pragma unroll
      for (int r = 0; r < 4; ++r) {
        float p = __expf(dots[mi][jt][r] - mx);
        dots[mi][jt][r] = p;
        sm += p;
      }
      cpk[mi][jt][0] = pk2u(dots[mi][jt][0], dots[mi][jt][1]);
      cpk[mi][jt][1] = pk2u(dots[mi][jt][2], dots[mi][jt][3]);
    }
    sm += __shfl_xor(sm, 16, 64);
    sm += __shfl_xor(sm, 32, 64);
    smv[mi] = sm;
  }

  __syncthreads();  // all waves done reading K

  // ---- stage V^T into same LDS: rows dd (512B each), chunk swizzle dd&7
#pragma unroll
  for (int i = 0; i < 8; ++i) {
    const int dd = (i * 4 + w) * 2 + (lane >> 5);
    gload_lds16(Vph + (size_t)dd * 256 + (((lane & 31) ^ (dd & 7)) * 8),
                (char*)KV + (i * 4 + w) * 1024);
  }
  __syncthreads();  // V staged

  // ---- PV per mi: pa assembled in-register from cpk via bpermute
#pragma unroll
  for (int mi = 0; mi < 2; ++mi) {
    f32x4 o[4];
#pragma unroll
    for (int j = 0; j < 4; ++j) o[j] = (f32x4){0.f, 0.f, 0.f, 0.f};
#pragma unroll
    for (int ks = 0; ks < 8; ++ks) {
      u32x4 wds;
#pragma unroll
      for (int m = 0; m < 4; ++m) {
        const int addr = ((((lane & 16) >> 3) + (m >> 1)) * 16 + lr) * 4;
        const int a0 = __builtin_amdgcn_ds_bpermute(
            addr, (int)cpk[mi][ks * 2][m & 1]);
        const int a1 = __builtin_amdgcn_ds_bpermute(
            addr, (int)cpk[mi][ks * 2 + 1][m & 1]);
        wds[m] = (unsigned)((lg >> 1) ? a1 : a0);
      }
      f16x8 pa = __builtin_bit_cast(f16x8, wds);
#pragma unroll
      for (int jt2 = 0; jt2 < 4; ++jt2) {
        const int dd = jt2 * 16 + lr;
        f16x8 bv = *(const f16x8*)((const char*)KV + dd * 512 +
                                   (((ks * 4 + lg) ^ (dd & 7)) * 16));
        o[jt2] = MFMA16(pa, bv, o[jt2]);
      }
    }

    // scale: sum for q = lg*4+r lives at lanes with lr == q
    float rs[4];
#pragma unroll
    for (int r = 0; r < 4; ++r)
      rs[r] = 1.f / __shfl(smv[mi], (lane & 48) + lg * 4 + r, 64);
#pragma unroll
    for (int jt2 = 0; jt2 < 4; ++jt2)
#pragma unroll
      for (int r = 0; r < 4; ++r) {
        const size_t row = (size_t)(b * 4096 + m0 + mi * 16 + lg * 4 + r);
        O[row * 1024 + h * 64 + jt2 * 16 + lr] = o[jt2][r] * rs[r];
      }
  }
}

// ---------------------------------------------------------------------------
extern "C" void kernel_launch(void* const* d_in, const int* in_sizes, int n_in,
                              void* d_out, int out_size, void* d_ws, size_t ws_size,
                              hipStream_t stream) {
  (void)in_sizes; (void)n_in; (void)out_size; (void)ws_size;
  const float* x  = (const float*)d_in[0];
  const float* Wq = (const float*)d_in[1];
  const float* Wk = (const float*)d_in[2];
  const float* Wv = (const float*)d_in[3];
  const float* pk = (const float*)d_in[4];
  const float* pv = (const float*)d_in[5];
  float* out = (float*)d_out;

  // ws layout (f16 halfwords), total ~52.4 MB.
  // The Qh region (33.5 MB) doubles as the f32 partials buffer (32 MB) for
  // stage1; gemm_q overwrites it later (stream-ordered after stage1_reduce).
  __fp16* Qh  = (__fp16*)d_ws;                       // 16384*1024 f16
  __fp16* WqT = Qh  + (size_t)16384 * 1024;          // 1024*1024 each
  __fp16* WkT = WqT + (size_t)1024 * 1024;
  __fp16* WvT = WkT + (size_t)1024 * 1024;
  __fp16* pkT = WvT + (size_t)1024 * 1024;           // 256*4096 each
  __fp16* pvT = pkT + (size_t)256 * 4096;
  __fp16* Xk  = pvT + (size_t)256 * 4096;            // 4*256*1024 each
  __fp16* Xv  = Xk  + (size_t)4 * 256 * 1024;
  __fp16* Kp  = Xv  + (size_t)4 * 256 * 1024;
  __fp16* Vpt = Kp  + (size_t)4 * 256 * 1024;
  float* Pk = (float*)d_ws;                          // 16*256*1024 f32 each
  float* Pv = Pk + (size_t)16 * 256 * 1024;

  const dim3 bb(256);

  // 0. one-time transposes (f32 -> f16)
  tr_cvt<<<dim3(32, 32), bb, 0, stream>>>(Wq, WqT, 1024, 1024);
  tr_cvt<<<dim3(32, 32), bb, 0, stream>>>(Wk, WkT, 1024, 1024);
  tr_cvt<<<dim3(32, 32), bb, 0, stream>>>(Wv, WvT, 1024, 1024);
  tr_cvt<<<dim3(8, 128), bb, 0, stream>>>(pk, pkT, 4096, 256);
  tr_cvt<<<dim3(8, 128), bb, 0, stream>>>(pv, pvT, 4096, 256);

  // 1. split-K low-rank projections of X + reduce
  stage1_partial<<<dim3(4, 16, 16), bb, 0, stream>>>(pkT, pvT, x, Pk, Pv);
  stage1_reduce<<<dim3(1024), bb, 0, stream>>>(Pk, Pv, Xk, Xv);

  // 2. Kp = Xk . Wk ; VpT = (Xv . Wv)^T
  bt64<<<dim3(4, 16, 4), bb, 0, stream>>>(Xk, 256LL * 1024, WkT, 0LL,
                                          Kp, 1024, 256LL * 1024);
  bt64<<<dim3(16, 4, 4), bb, 0, stream>>>(WvT, 0LL, Xv, 256LL * 1024,
                                          Vpt, 256, 1024LL * 256);

  // 3. Q projection (overwrites partials region - stream-ordered)
  gemm_q<<<dim3(128, 8), bb, 0, stream>>>(x, WqT, Qh);

  // 4. attention (32KB LDS, swapped QK, in-register P)
  attn_k<<<dim3(2048), bb, 0, stream>>>(Qh, Kp, Vpt, out);
}